// Round 6
// baseline (9898.713 us; speedup 1.0000x reference)
//
#include <hip/hip_runtime.h>
#include <hip/hip_bf16.h>

// LlamaMLPInfer: SwiGLU MLP with group(128)-dequantized int4 weights.
// R6: revert to R4 single-barrier pipeline; BK 64->32 so LDS = 64KB (gateup)
// / 48KB (down) -> 2 blocks/CU (TLP to hide stage/drain latency).
// T1 XCD-chunked grid swizzle, T2 XOR chunk swizzle, setprio around MFMA.

#define HDIM 4096
#define IDIM 14336
#define MTOK 4096
#define GRP 128

typedef __attribute__((ext_vector_type(8))) short bf16x8;
typedef __attribute__((ext_vector_type(4))) float f32x4;
typedef __attribute__((ext_vector_type(4))) unsigned short u16x4;

__device__ __forceinline__ unsigned short f2bf(float f) {
  union { float f; unsigned int u; } v; v.f = f;
  return (unsigned short)((v.u + 0x7fffu + ((v.u >> 16) & 1u)) >> 16);  // RNE
}
// pack two f32 -> two bf16 (truncate): low16 = bf16(a), high16 = bf16(b)
__device__ __forceinline__ unsigned pk2(float a, float b) {
  union { float f; unsigned u; } ua, ub; ua.f = a; ub.f = b;
  return __builtin_amdgcn_perm(ub.u, ua.u, 0x07060302u);
}

// ---------------- x fp32 -> bf16 ----------------
__global__ __launch_bounds__(256) void cvt_x_kernel(const float* __restrict__ x,
                                                    unsigned short* __restrict__ xb) {
  const int n = MTOK * HDIM;
  const int stride = gridDim.x * 256 * 4;
  for (int i = (blockIdx.x * 256 + threadIdx.x) * 4; i < n; i += stride) {
    float4 v = *reinterpret_cast<const float4*>(x + i);
    u16x4 o;
    o[0] = f2bf(v.x); o[1] = f2bf(v.y); o[2] = f2bf(v.z); o[3] = f2bf(v.w);
    *reinterpret_cast<u16x4*>(xb + i) = o;
  }
}

// ================= fused gate+up GEMM =================
// 256x128 tile, BK=32, 512 thr (8 waves, 4Mx2N). 1 barrier/K-step.
__global__ __launch_bounds__(512, 4) void gateup_kernel(
    const unsigned short* __restrict__ xb,
    const int* __restrict__ gq, const float* __restrict__ gs,
    const int* __restrict__ uq, const float* __restrict__ us,
    unsigned short* __restrict__ inter)
{
  __shared__ unsigned short As[2 * 256 * 32];  // 32 KB dbuf
  __shared__ unsigned short Bg[2 * 128 * 32];  // 16 KB dbuf
  __shared__ unsigned short Bu[2 * 128 * 32];  // 16 KB dbuf

  const int tid  = threadIdx.x;
  const int lane = tid & 63;
  const int wid  = tid >> 6;
  const int wm   = wid >> 1, wn = wid & 1;
  // XCD-chunked swizzle: 1792 blocks, 8 XCDs, 224 contiguous logicals/XCD.
  const int p  = blockIdx.x;
  const int l  = (p & 7) * 224 + (p >> 3);
  const int m0 = (l & 15) * 256;
  const int n0 = (l >> 4) * 128;
  const int lr = lane & 15, lc = lane >> 4;

  // A staging (global_load_lds, linear dest, pre-swizzled source col)
  const int ra    = tid >> 2;                          // 0..127 (+ it*128)
  const int scolA = ((tid & 3) ^ (ra & 3)) << 3;
  const unsigned short* pa = xb + (long)(m0 + ra) * HDIM + scolA;
  // per-it wave-uniform LDS bases (elems): it*4096 + wid*512
  unsigned short* lbase = (unsigned short*)As + wid * 512;

  // B staging (reg-staged, swizzled ds_write)
  const int rb   = tid >> 2;                           // 0..127
  const int cbI  = (tid & 3) << 3;                     // int col in K-tile
  const int sidx = rb * 32 + (((tid & 3) ^ (rb & 3)) << 3);
  const int*   pg = gq + (long)(n0 + rb) * HDIM + cbI;
  const int*   pu = uq + (long)(n0 + rb) * HDIM + cbI;
  const float* psg = gs + (n0 + rb) * (HDIM / GRP);
  const float* psu = us + (n0 + rb) * (HDIM / GRP);

  int4 qg0, qg1, qu0, qu1;
  float sg, su;

#define GU_ISSUEA(KTA, WRP) do {                                              \
    const unsigned short* g_ = pa + (KTA) * 32;                               \
    unsigned short* l_ = lbase + (WRP) * 8192;                                \
    __builtin_amdgcn_global_load_lds(                                         \
        (const __attribute__((address_space(1))) unsigned int*)g_,            \
        (__attribute__((address_space(3))) unsigned int*)l_, 16, 0, 0);       \
    __builtin_amdgcn_global_load_lds(                                         \
        (const __attribute__((address_space(1))) unsigned int*)(g_ + (long)128 * HDIM), \
        (__attribute__((address_space(3))) unsigned int*)(l_ + 4096), 16, 0, 0); \
  } while (0)

#define GU_LOADB(KT) do { const int kk_ = (KT) << 5;                          \
    qg0 = *(const int4*)(pg + kk_); qg1 = *(const int4*)(pg + kk_ + 4);       \
    qu0 = *(const int4*)(pu + kk_); qu1 = *(const int4*)(pu + kk_ + 4);       \
    sg = psg[(KT) >> 2]; su = psu[(KT) >> 2];                                 \
  } while (0)

#define GU_WRITEB(WRP) do {                                                   \
    unsigned short* Bg_ = (unsigned short*)Bg + (WRP) * 4096;                 \
    unsigned short* Bu_ = (unsigned short*)Bu + (WRP) * 4096;                 \
    uint4 w_;                                                                 \
    w_.x = pk2((float)qg0.x * sg, (float)qg0.y * sg);                         \
    w_.y = pk2((float)qg0.z * sg, (float)qg0.w * sg);                         \
    w_.z = pk2((float)qg1.x * sg, (float)qg1.y * sg);                         \
    w_.w = pk2((float)qg1.z * sg, (float)qg1.w * sg);                         \
    *(uint4*)&Bg_[sidx] = w_;                                                 \
    w_.x = pk2((float)qu0.x * su, (float)qu0.y * su);                         \
    w_.y = pk2((float)qu0.z * su, (float)qu0.w * su);                         \
    w_.z = pk2((float)qu1.x * su, (float)qu1.y * su);                         \
    w_.w = pk2((float)qu1.z * su, (float)qu1.w * su);                         \
    *(uint4*)&Bu_[sidx] = w_;                                                 \
  } while (0)

  f32x4 accg[4][4], accu[4][4];
  const f32x4 zero = {0.f, 0.f, 0.f, 0.f};
#pragma unroll
  for (int i = 0; i < 4; ++i)
#pragma unroll
    for (int j = 0; j < 4; ++j) { accg[i][j] = zero; accu[i][j] = zero; }

  // prologue: stage tile 0 -> parity 0
  GU_ISSUEA(0, 0);
  GU_LOADB(0);
  GU_WRITEB(0);
  __syncthreads();

  const int NK = HDIM / 32;   // 128
#pragma unroll 1
  for (int kt = 0; kt < NK; ++kt) {
    const int RD = kt & 1, WR = RD ^ 1;
    const int ktn = (kt + 1 < NK) ? kt + 1 : kt;
    GU_ISSUEA(ktn, WR);
    __builtin_amdgcn_sched_barrier(0);
    GU_LOADB(ktn);
    __builtin_amdgcn_sched_barrier(0);
    // ---- compute tile kt ----
    {
      const unsigned short* Ab  = (const unsigned short*)As + RD * 8192;
      const unsigned short* Bgb = (const unsigned short*)Bg + RD * 4096;
      const unsigned short* Bub = (const unsigned short*)Bu + RD * 4096;
      const int soff = (lc ^ (lr & 3)) << 3;
      bf16x8 af[4];
      __builtin_amdgcn_s_setprio(1);
#pragma unroll
      for (int mi = 0; mi < 4; ++mi)
        af[mi] = *(const bf16x8*)&Ab[(wm * 64 + mi * 16 + lr) * 32 + soff];
#pragma unroll
      for (int ni = 0; ni < 4; ++ni) {
        bf16x8 bg = *(const bf16x8*)&Bgb[(wn * 64 + ni * 16 + lr) * 32 + soff];
        bf16x8 bu = *(const bf16x8*)&Bub[(wn * 64 + ni * 16 + lr) * 32 + soff];
#pragma unroll
        for (int mi = 0; mi < 4; ++mi) {
          accg[mi][ni] = __builtin_amdgcn_mfma_f32_16x16x32_bf16(af[mi], bg, accg[mi][ni], 0, 0, 0);
          accu[mi][ni] = __builtin_amdgcn_mfma_f32_16x16x32_bf16(af[mi], bu, accu[mi][ni], 0, 0, 0);
        }
      }
      __builtin_amdgcn_s_setprio(0);
    }
    __builtin_amdgcn_sched_barrier(0);
    GU_WRITEB(WR);             // dequant next tile -> other parity
    __syncthreads();           // one barrier per K-step
  }

  // ---- epilogue: silu(g)*u -> bf16 ----
  const int r0 = m0 + wm * 64, c0 = n0 + wn * 64;
#pragma unroll
  for (int mi = 0; mi < 4; ++mi)
#pragma unroll
    for (int ni = 0; ni < 4; ++ni)
#pragma unroll
      for (int r = 0; r < 4; ++r) {
        float g = accg[mi][ni][r], u = accu[mi][ni][r];
        float sv = g / (1.f + __expf(-g));
        int row = r0 + mi * 16 + lc * 4 + r;
        int col = c0 + ni * 16 + lr;
        inter[(long)row * IDIM + col] = f2bf(sv * u);
      }
#undef GU_ISSUEA
#undef GU_LOADB
#undef GU_WRITEB
}

// ================= down GEMM =================
// 256x128 tile, BK=32, 1 barrier/K-step, 48KB LDS.
__global__ __launch_bounds__(512, 4) void down_kernel(
    const unsigned short* __restrict__ inter,
    const int* __restrict__ dq, const float* __restrict__ dsc,
    float* __restrict__ out)
{
  __shared__ unsigned short As[2 * 256 * 32];  // 32 KB dbuf
  __shared__ unsigned short Bs[2 * 128 * 32];  // 16 KB dbuf

  const int tid  = threadIdx.x;
  const int lane = tid & 63;
  const int wid  = tid >> 6;
  const int wm   = wid >> 1, wn = wid & 1;
  const int p  = blockIdx.x;                 // 512 blocks
  const int l  = (p & 7) * 64 + (p >> 3);
  const int m0 = (l & 15) * 256;
  const int n0 = (l >> 4) * 128;
  const int lr = lane & 15, lc = lane >> 4;

  const int ra    = tid >> 2;
  const int scolA = ((tid & 3) ^ (ra & 3)) << 3;
  const unsigned short* pa = inter + (long)(m0 + ra) * IDIM + scolA;
  unsigned short* lbase = (unsigned short*)As + wid * 512;

  const int rb   = tid >> 2;
  const int cbI  = (tid & 3) << 3;
  const int sidx = rb * 32 + (((tid & 3) ^ (rb & 3)) << 3);
  const int*   pd = dq + (long)(n0 + rb) * IDIM + cbI;
  const float* ps = dsc + (n0 + rb) * (IDIM / GRP);

  int4 qd0, qd1;
  float sd;

#define DN_ISSUEA(KTA, WRP) do {                                              \
    const unsigned short* g_ = pa + (KTA) * 32;                               \
    unsigned short* l_ = lbase + (WRP) * 8192;                                \
    __builtin_amdgcn_global_load_lds(                                         \
        (const __attribute__((address_space(1))) unsigned int*)g_,            \
        (__attribute__((address_space(3))) unsigned int*)l_, 16, 0, 0);       \
    __builtin_amdgcn_global_load_lds(                                         \
        (const __attribute__((address_space(1))) unsigned int*)(g_ + (long)128 * IDIM), \
        (__attribute__((address_space(3))) unsigned int*)(l_ + 4096), 16, 0, 0); \
  } while (0)

#define DN_LOADB(KT) do { const int kk_ = (KT) << 5;                          \
    qd0 = *(const int4*)(pd + kk_); qd1 = *(const int4*)(pd + kk_ + 4);       \
    sd = ps[(KT) >> 2];                                                       \
  } while (0)

#define DN_WRITEB(WRP) do {                                                   \
    unsigned short* B_ = (unsigned short*)Bs + (WRP) * 4096;                  \
    uint4 w_;                                                                 \
    w_.x = pk2((float)qd0.x * sd, (float)qd0.y * sd);                         \
    w_.y = pk2((float)qd0.z * sd, (float)qd0.w * sd);                         \
    w_.z = pk2((float)qd1.x * sd, (float)qd1.y * sd);                         \
    w_.w = pk2((float)qd1.z * sd, (float)qd1.w * sd);                         \
    *(uint4*)&B_[sidx] = w_;                                                  \
  } while (0)

  f32x4 acc[4][4];
  const f32x4 zero = {0.f, 0.f, 0.f, 0.f};
#pragma unroll
  for (int i = 0; i < 4; ++i)
#pragma unroll
    for (int j = 0; j < 4; ++j) acc[i][j] = zero;

  DN_ISSUEA(0, 0);
  DN_LOADB(0);
  DN_WRITEB(0);
  __syncthreads();

  const int NKD = IDIM / 32;   // 448
#pragma unroll 1
  for (int kt = 0; kt < NKD; ++kt) {
    const int RD = kt & 1, WR = RD ^ 1;
    const int ktn = (kt + 1 < NKD) ? kt + 1 : kt;
    DN_ISSUEA(ktn, WR);
    __builtin_amdgcn_sched_barrier(0);
    DN_LOADB(ktn);
    __builtin_amdgcn_sched_barrier(0);
    {
      const unsigned short* Ab = (const unsigned short*)As + RD * 8192;
      const unsigned short* Bb = (const unsigned short*)Bs + RD * 4096;
      const int soff = (lc ^ (lr & 3)) << 3;
      bf16x8 af[4], bfr[4];
      __builtin_amdgcn_s_setprio(1);
#pragma unroll
      for (int mi = 0; mi < 4; ++mi)
        af[mi] = *(const bf16x8*)&Ab[(wm * 64 + mi * 16 + lr) * 32 + soff];
#pragma unroll
      for (int ni = 0; ni < 4; ++ni)
        bfr[ni] = *(const bf16x8*)&Bb[(wn * 64 + ni * 16 + lr) * 32 + soff];
#pragma unroll
      for (int ni = 0; ni < 4; ++ni)
#pragma unroll
        for (int mi = 0; mi < 4; ++mi)
          acc[mi][ni] = __builtin_amdgcn_mfma_f32_16x16x32_bf16(af[mi], bfr[ni], acc[mi][ni], 0, 0, 0);
      __builtin_amdgcn_s_setprio(0);
    }
    __builtin_amdgcn_sched_barrier(0);
    DN_WRITEB(WR);
    __syncthreads();
  }

  const int r0 = m0 + wm * 64, c0 = n0 + wn * 64;
#pragma unroll
  for (int mi = 0; mi < 4; ++mi)
#pragma unroll
    for (int ni = 0; ni < 4; ++ni)
#pragma unroll
      for (int r = 0; r < 4; ++r) {
        int row = r0 + mi * 16 + lc * 4 + r;
        int col = c0 + ni * 16 + lr;
        out[(long)row * HDIM + col] = acc[mi][ni][r];
      }
#undef DN_ISSUEA
#undef DN_LOADB
#undef DN_WRITEB
}

extern "C" void kernel_launch(void* const* d_in, const int* in_sizes, int n_in,
                              void* d_out, int out_size, void* d_ws, size_t ws_size,
                              hipStream_t stream) {
  const float* x   = (const float*)d_in[0];
  const int*   gq  = (const int*)d_in[1];
  const float* gsc = (const float*)d_in[2];
  const int*   uq  = (const int*)d_in[3];
  const float* usc = (const float*)d_in[4];
  const int*   dq  = (const int*)d_in[5];
  const float* dsc = (const float*)d_in[6];
  float* out = (float*)d_out;

  // ws layout: xb [MTOK*HDIM] bf16 (32 MiB) | inter [MTOK*IDIM] bf16 (112 MiB)
  unsigned short* xb    = (unsigned short*)d_ws;
  unsigned short* inter = xb + (size_t)MTOK * HDIM;

  hipLaunchKernelGGL(cvt_x_kernel, dim3(2048), dim3(256), 0, stream, x, xb);
  hipLaunchKernelGGL(gateup_kernel, dim3(1792), dim3(512), 0, stream,
                     xb, gq, gsc, uq, usc, inter);
  hipLaunchKernelGGL(down_kernel, dim3(512), dim3(512), 0, stream,
                     inter, dq, dsc, out);
}

// Round 7
// 2494.992 us; speedup vs baseline: 3.9674x; 3.9674x over previous
//
#include <hip/hip_runtime.h>
#include <hip/hip_bf16.h>

// LlamaMLPInfer: SwiGLU MLP with group(128)-dequantized int4 weights.
// R7: R6 structure (BK=32, 1 barrier/K-step, dbuf A+B, LDS 64/48 KB)
// with TWO fixes: __launch_bounds__(512,2) (empirically: arg2 = blocks/CU;
// (512,4) capped VGPR at 64 -> 40GB spill traffic), and BK=32-correct
// LDS swizzle ch ^= (row>>1)&3 (row&3 collided 4-way at 64B rows).

#define HDIM 4096
#define IDIM 14336
#define MTOK 4096
#define GRP 128

typedef __attribute__((ext_vector_type(8))) short bf16x8;
typedef __attribute__((ext_vector_type(4))) float f32x4;
typedef __attribute__((ext_vector_type(4))) unsigned short u16x4;

__device__ __forceinline__ unsigned short f2bf(float f) {
  union { float f; unsigned int u; } v; v.f = f;
  return (unsigned short)((v.u + 0x7fffu + ((v.u >> 16) & 1u)) >> 16);  // RNE
}
// pack two f32 -> two bf16 (truncate): low16 = bf16(a), high16 = bf16(b)
__device__ __forceinline__ unsigned pk2(float a, float b) {
  union { float f; unsigned u; } ua, ub; ua.f = a; ub.f = b;
  return __builtin_amdgcn_perm(ub.u, ua.u, 0x07060302u);
}

// ---------------- x fp32 -> bf16 ----------------
__global__ __launch_bounds__(256) void cvt_x_kernel(const float* __restrict__ x,
                                                    unsigned short* __restrict__ xb) {
  const int n = MTOK * HDIM;
  const int stride = gridDim.x * 256 * 4;
  for (int i = (blockIdx.x * 256 + threadIdx.x) * 4; i < n; i += stride) {
    float4 v = *reinterpret_cast<const float4*>(x + i);
    u16x4 o;
    o[0] = f2bf(v.x); o[1] = f2bf(v.y); o[2] = f2bf(v.z); o[3] = f2bf(v.w);
    *reinterpret_cast<u16x4*>(xb + i) = o;
  }
}

// ================= fused gate+up GEMM =================
// 256x128 tile, BK=32, 512 thr (8 waves, 4Mx2N). 1 barrier/K-step. 64KB LDS.
__global__ __launch_bounds__(512, 2) void gateup_kernel(
    const unsigned short* __restrict__ xb,
    const int* __restrict__ gq, const float* __restrict__ gs,
    const int* __restrict__ uq, const float* __restrict__ us,
    unsigned short* __restrict__ inter)
{
  __shared__ unsigned short As[2 * 256 * 32];  // 32 KB dbuf
  __shared__ unsigned short Bg[2 * 128 * 32];  // 16 KB dbuf
  __shared__ unsigned short Bu[2 * 128 * 32];  // 16 KB dbuf

  const int tid  = threadIdx.x;
  const int lane = tid & 63;
  const int wid  = tid >> 6;
  const int wm   = wid >> 1, wn = wid & 1;
  // XCD-chunked swizzle: 1792 blocks, 8 XCDs, 224 contiguous logicals/XCD.
  const int p  = blockIdx.x;
  const int l  = (p & 7) * 224 + (p >> 3);
  const int m0 = (l & 15) * 256;
  const int n0 = (l >> 4) * 128;
  const int lr = lane & 15, lc = lane >> 4;

  // A staging (global_load_lds, linear dest, pre-swizzled source col).
  // swizzle: chunk ^= (row>>1)&3  (row is 64B = 4 chunks; +128 rows invariant)
  const int ra    = tid >> 2;                          // 0..127 (+128 for 2nd)
  const int scolA = ((tid & 3) ^ ((ra >> 1) & 3)) << 3;
  const unsigned short* pa = xb + (long)(m0 + ra) * HDIM + scolA;
  unsigned short* lbase = (unsigned short*)As + wid * 512;

  // B staging (reg-staged, swizzled ds_write)
  const int rb   = tid >> 2;                           // 0..127
  const int cbI  = (tid & 3) << 3;                     // int col in K-tile
  const int sidx = rb * 32 + (((tid & 3) ^ ((rb >> 1) & 3)) << 3);
  const int*   pg = gq + (long)(n0 + rb) * HDIM + cbI;
  const int*   pu = uq + (long)(n0 + rb) * HDIM + cbI;
  const float* psg = gs + (n0 + rb) * (HDIM / GRP);
  const float* psu = us + (n0 + rb) * (HDIM / GRP);

  int4 qg0, qg1, qu0, qu1;
  float sg, su;

#define GU_ISSUEA(KTA, WRP) do {                                              \
    const unsigned short* g_ = pa + (KTA) * 32;                               \
    unsigned short* l_ = lbase + (WRP) * 8192;                                \
    __builtin_amdgcn_global_load_lds(                                         \
        (const __attribute__((address_space(1))) unsigned int*)g_,            \
        (__attribute__((address_space(3))) unsigned int*)l_, 16, 0, 0);       \
    __builtin_amdgcn_global_load_lds(                                         \
        (const __attribute__((address_space(1))) unsigned int*)(g_ + (long)128 * HDIM), \
        (__attribute__((address_space(3))) unsigned int*)(l_ + 4096), 16, 0, 0); \
  } while (0)

#define GU_LOADB(KT) do { const int kk_ = (KT) << 5;                          \
    qg0 = *(const int4*)(pg + kk_); qg1 = *(const int4*)(pg + kk_ + 4);       \
    qu0 = *(const int4*)(pu + kk_); qu1 = *(const int4*)(pu + kk_ + 4);       \
    sg = psg[(KT) >> 2]; su = psu[(KT) >> 2];                                 \
  } while (0)

#define GU_WRITEB(WRP) do {                                                   \
    unsigned short* Bg_ = (unsigned short*)Bg + (WRP) * 4096;                 \
    unsigned short* Bu_ = (unsigned short*)Bu + (WRP) * 4096;                 \
    uint4 w_;                                                                 \
    w_.x = pk2((float)qg0.x * sg, (float)qg0.y * sg);                         \
    w_.y = pk2((float)qg0.z * sg, (float)qg0.w * sg);                         \
    w_.z = pk2((float)qg1.x * sg, (float)qg1.y * sg);                         \
    w_.w = pk2((float)qg1.z * sg, (float)qg1.w * sg);                         \
    *(uint4*)&Bg_[sidx] = w_;                                                 \
    w_.x = pk2((float)qu0.x * su, (float)qu0.y * su);                         \
    w_.y = pk2((float)qu0.z * su, (float)qu0.w * su);                         \
    w_.z = pk2((float)qu1.x * su, (float)qu1.y * su);                         \
    w_.w = pk2((float)qu1.z * su, (float)qu1.w * su);                         \
    *(uint4*)&Bu_[sidx] = w_;                                                 \
  } while (0)

  f32x4 accg[4][4], accu[4][4];
  const f32x4 zero = {0.f, 0.f, 0.f, 0.f};
#pragma unroll
  for (int i = 0; i < 4; ++i)
#pragma unroll
    for (int j = 0; j < 4; ++j) { accg[i][j] = zero; accu[i][j] = zero; }

  // prologue: stage tile 0 -> parity 0
  GU_ISSUEA(0, 0);
  GU_LOADB(0);
  GU_WRITEB(0);
  __syncthreads();

  const int NK = HDIM / 32;   // 128
#pragma unroll 1
  for (int kt = 0; kt < NK; ++kt) {
    const int RD = kt & 1, WR = RD ^ 1;
    const int ktn = (kt + 1 < NK) ? kt + 1 : kt;
    GU_ISSUEA(ktn, WR);
    __builtin_amdgcn_sched_barrier(0);
    GU_LOADB(ktn);
    __builtin_amdgcn_sched_barrier(0);
    // ---- compute tile kt ----
    {
      const unsigned short* Ab  = (const unsigned short*)As + RD * 8192;
      const unsigned short* Bgb = (const unsigned short*)Bg + RD * 4096;
      const unsigned short* Bub = (const unsigned short*)Bu + RD * 4096;
      const int soff = (lc ^ ((lr >> 1) & 3)) << 3;
      bf16x8 af[4];
      __builtin_amdgcn_s_setprio(1);
#pragma unroll
      for (int mi = 0; mi < 4; ++mi)
        af[mi] = *(const bf16x8*)&Ab[(wm * 64 + mi * 16 + lr) * 32 + soff];
#pragma unroll
      for (int ni = 0; ni < 4; ++ni) {
        bf16x8 bg = *(const bf16x8*)&Bgb[(wn * 64 + ni * 16 + lr) * 32 + soff];
        bf16x8 bu = *(const bf16x8*)&Bub[(wn * 64 + ni * 16 + lr) * 32 + soff];
#pragma unroll
        for (int mi = 0; mi < 4; ++mi) {
          accg[mi][ni] = __builtin_amdgcn_mfma_f32_16x16x32_bf16(af[mi], bg, accg[mi][ni], 0, 0, 0);
          accu[mi][ni] = __builtin_amdgcn_mfma_f32_16x16x32_bf16(af[mi], bu, accu[mi][ni], 0, 0, 0);
        }
      }
      __builtin_amdgcn_s_setprio(0);
    }
    __builtin_amdgcn_sched_barrier(0);
    GU_WRITEB(WR);             // dequant next tile -> other parity
    __syncthreads();           // one barrier per K-step
  }

  // ---- epilogue: silu(g)*u -> bf16 ----
  const int r0 = m0 + wm * 64, c0 = n0 + wn * 64;
#pragma unroll
  for (int mi = 0; mi < 4; ++mi)
#pragma unroll
    for (int ni = 0; ni < 4; ++ni)
#pragma unroll
      for (int r = 0; r < 4; ++r) {
        float g = accg[mi][ni][r], u = accu[mi][ni][r];
        float sv = g / (1.f + __expf(-g));
        int row = r0 + mi * 16 + lc * 4 + r;
        int col = c0 + ni * 16 + lr;
        inter[(long)row * IDIM + col] = f2bf(sv * u);
      }
#undef GU_ISSUEA
#undef GU_LOADB
#undef GU_WRITEB
}

// ================= down GEMM =================
// 256x128 tile, BK=32, 1 barrier/K-step, 48KB LDS.
__global__ __launch_bounds__(512, 2) void down_kernel(
    const unsigned short* __restrict__ inter,
    const int* __restrict__ dq, const float* __restrict__ dsc,
    float* __restrict__ out)
{
  __shared__ unsigned short As[2 * 256 * 32];  // 32 KB dbuf
  __shared__ unsigned short Bs[2 * 128 * 32];  // 16 KB dbuf

  const int tid  = threadIdx.x;
  const int lane = tid & 63;
  const int wid  = tid >> 6;
  const int wm   = wid >> 1, wn = wid & 1;
  const int p  = blockIdx.x;                 // 512 blocks
  const int l  = (p & 7) * 64 + (p >> 3);
  const int m0 = (l & 15) * 256;
  const int n0 = (l >> 4) * 128;
  const int lr = lane & 15, lc = lane >> 4;

  const int ra    = tid >> 2;
  const int scolA = ((tid & 3) ^ ((ra >> 1) & 3)) << 3;
  const unsigned short* pa = inter + (long)(m0 + ra) * IDIM + scolA;
  unsigned short* lbase = (unsigned short*)As + wid * 512;

  const int rb   = tid >> 2;
  const int cbI  = (tid & 3) << 3;
  const int sidx = rb * 32 + (((tid & 3) ^ ((rb >> 1) & 3)) << 3);
  const int*   pd = dq + (long)(n0 + rb) * IDIM + cbI;
  const float* ps = dsc + (n0 + rb) * (IDIM / GRP);

  int4 qd0, qd1;
  float sd;

#define DN_ISSUEA(KTA, WRP) do {                                              \
    const unsigned short* g_ = pa + (KTA) * 32;                               \
    unsigned short* l_ = lbase + (WRP) * 8192;                                \
    __builtin_amdgcn_global_load_lds(                                         \
        (const __attribute__((address_space(1))) unsigned int*)g_,            \
        (__attribute__((address_space(3))) unsigned int*)l_, 16, 0, 0);       \
    __builtin_amdgcn_global_load_lds(                                         \
        (const __attribute__((address_space(1))) unsigned int*)(g_ + (long)128 * IDIM), \
        (__attribute__((address_space(3))) unsigned int*)(l_ + 4096), 16, 0, 0); \
  } while (0)

#define DN_LOADB(KT) do { const int kk_ = (KT) << 5;                          \
    qd0 = *(const int4*)(pd + kk_); qd1 = *(const int4*)(pd + kk_ + 4);       \
    sd = ps[(KT) >> 2];                                                       \
  } while (0)

#define DN_WRITEB(WRP) do {                                                   \
    unsigned short* B_ = (unsigned short*)Bs + (WRP) * 4096;                  \
    uint4 w_;                                                                 \
    w_.x = pk2((float)qd0.x * sd, (float)qd0.y * sd);                         \
    w_.y = pk2((float)qd0.z * sd, (float)qd0.w * sd);                         \
    w_.z = pk2((float)qd1.x * sd, (float)qd1.y * sd);                         \
    w_.w = pk2((float)qd1.z * sd, (float)qd1.w * sd);                         \
    *(uint4*)&B_[sidx] = w_;                                                  \
  } while (0)

  f32x4 acc[4][4];
  const f32x4 zero = {0.f, 0.f, 0.f, 0.f};
#pragma unroll
  for (int i = 0; i < 4; ++i)
#pragma unroll
    for (int j = 0; j < 4; ++j) acc[i][j] = zero;

  DN_ISSUEA(0, 0);
  DN_LOADB(0);
  DN_WRITEB(0);
  __syncthreads();

  const int NKD = IDIM / 32;   // 448
#pragma unroll 1
  for (int kt = 0; kt < NKD; ++kt) {
    const int RD = kt & 1, WR = RD ^ 1;
    const int ktn = (kt + 1 < NKD) ? kt + 1 : kt;
    DN_ISSUEA(ktn, WR);
    __builtin_amdgcn_sched_barrier(0);
    DN_LOADB(ktn);
    __builtin_amdgcn_sched_barrier(0);
    {
      const unsigned short* Ab = (const unsigned short*)As + RD * 8192;
      const unsigned short* Bb = (const unsigned short*)Bs + RD * 4096;
      const int soff = (lc ^ ((lr >> 1) & 3)) << 3;
      bf16x8 af[4], bfr[4];
      __builtin_amdgcn_s_setprio(1);
#pragma unroll
      for (int mi = 0; mi < 4; ++mi)
        af[mi] = *(const bf16x8*)&Ab[(wm * 64 + mi * 16 + lr) * 32 + soff];
#pragma unroll
      for (int ni = 0; ni < 4; ++ni)
        bfr[ni] = *(const bf16x8*)&Bb[(wn * 64 + ni * 16 + lr) * 32 + soff];
#pragma unroll
      for (int ni = 0; ni < 4; ++ni)
#pragma unroll
        for (int mi = 0; mi < 4; ++mi)
          acc[mi][ni] = __builtin_amdgcn_mfma_f32_16x16x32_bf16(af[mi], bfr[ni], acc[mi][ni], 0, 0, 0);
      __builtin_amdgcn_s_setprio(0);
    }
    __builtin_amdgcn_sched_barrier(0);
    DN_WRITEB(WR);
    __syncthreads();
  }

  const int r0 = m0 + wm * 64, c0 = n0 + wn * 64;
#pragma unroll
  for (int mi = 0; mi < 4; ++mi)
#pragma unroll
    for (int ni = 0; ni < 4; ++ni)
#pragma unroll
      for (int r = 0; r < 4; ++r) {
        int row = r0 + mi * 16 + lc * 4 + r;
        int col = c0 + ni * 16 + lr;
        out[(long)row * HDIM + col] = acc[mi][ni][r];
      }
#undef DN_ISSUEA
#undef DN_LOADB
#undef DN_WRITEB
}

extern "C" void kernel_launch(void* const* d_in, const int* in_sizes, int n_in,
                              void* d_out, int out_size, void* d_ws, size_t ws_size,
                              hipStream_t stream) {
  const float* x   = (const float*)d_in[0];
  const int*   gq  = (const int*)d_in[1];
  const float* gsc = (const float*)d_in[2];
  const int*   uq  = (const int*)d_in[3];
  const float* usc = (const float*)d_in[4];
  const int*   dq  = (const int*)d_in[5];
  const float* dsc = (const float*)d_in[6];
  float* out = (float*)d_out;

  // ws layout: xb [MTOK*HDIM] bf16 (32 MiB) | inter [MTOK*IDIM] bf16 (112 MiB)
  unsigned short* xb    = (unsigned short*)d_ws;
  unsigned short* inter = xb + (size_t)MTOK * HDIM;

  hipLaunchKernelGGL(cvt_x_kernel, dim3(2048), dim3(256), 0, stream, x, xb);
  hipLaunchKernelGGL(gateup_kernel, dim3(1792), dim3(512), 0, stream,
                     xb, gq, gsc, uq, usc, inter);
  hipLaunchKernelGGL(down_kernel, dim3(512), dim3(512), 0, stream,
                     inter, dq, dsc, out);
}

// Round 8
// 1952.008 us; speedup vs baseline: 5.0710x; 1.2782x over previous
//
#include <hip/hip_runtime.h>
#include <hip/hip_bf16.h>

// LlamaMLPInfer: SwiGLU MLP with group(128)-dequantized int4 weights.
// R8: pre-dequantize weights to bf16 in ws (one memory-bound pass), making
// both GEMMs clean bf16 GEMMs with pure global_load_lds staging (m97-style
// 1-barrier dbuf loop). Removes the 16x-redundant dequant VALU + B ds_write
// round-trip from the GEMM critical path. Fallback to inline-dequant path
// (R4 structure) if ws_size is too small.

#define HDIM 4096
#define IDIM 14336
#define MTOK 4096
#define GRP 128

typedef __attribute__((ext_vector_type(8))) short bf16x8;
typedef __attribute__((ext_vector_type(4))) float f32x4;
typedef __attribute__((ext_vector_type(4))) unsigned short u16x4;

#define WAIT_VM0 asm volatile("s_waitcnt vmcnt(0)" ::: "memory")
#define SBAR     __builtin_amdgcn_s_barrier()
#define SCHB     __builtin_amdgcn_sched_barrier(0)

__device__ __forceinline__ unsigned short f2bf(float f) {
  union { float f; unsigned int u; } v; v.f = f;
  return (unsigned short)((v.u + 0x7fffu + ((v.u >> 16) & 1u)) >> 16);  // RNE
}
// pack two f32 -> two bf16 (truncate): low16 = bf16(a), high16 = bf16(b)
__device__ __forceinline__ unsigned pk2(float a, float b) {
  union { float f; unsigned u; } ua, ub; ua.f = a; ub.f = b;
  return __builtin_amdgcn_perm(ub.u, ua.u, 0x07060302u);
}

#define GLD16(G, L)                                                           \
  __builtin_amdgcn_global_load_lds(                                           \
      (const __attribute__((address_space(1))) unsigned int*)(G),             \
      (__attribute__((address_space(3))) unsigned int*)(L), 16, 0, 0)

// ---------------- x fp32 -> bf16 ----------------
__global__ __launch_bounds__(256) void cvt_x_kernel(const float* __restrict__ x,
                                                    unsigned short* __restrict__ xb) {
  const int n = MTOK * HDIM;
  const int stride = gridDim.x * 256 * 4;
  for (int i = (blockIdx.x * 256 + threadIdx.x) * 4; i < n; i += stride) {
    float4 v = *reinterpret_cast<const float4*>(x + i);
    u16x4 o;
    o[0] = f2bf(v.x); o[1] = f2bf(v.y); o[2] = f2bf(v.z); o[3] = f2bf(v.w);
    *reinterpret_cast<u16x4*>(xb + i) = o;
  }
}

// ---------------- weight dequant: int32[O][In] * s[O][In/128] -> bf16 ----------------
// grid (In/2048, O), block 256; each thread: 8 elems.
__global__ __launch_bounds__(256) void deq_kernel(const int* __restrict__ q,
                                                  const float* __restrict__ s,
                                                  unsigned short* __restrict__ w,
                                                  int In) {
  const int row  = blockIdx.y;
  const int col0 = blockIdx.x * 2048 + threadIdx.x * 8;
  const long base = (long)row * In + col0;
  const float sc = s[row * (In / GRP) + (col0 >> 7)];
  const int4* p = (const int4*)(q + base);
  int4 a0 = p[0], a1 = p[1];
  uint4 o;
  o.x = pk2((float)a0.x * sc, (float)a0.y * sc);
  o.y = pk2((float)a0.z * sc, (float)a0.w * sc);
  o.z = pk2((float)a1.x * sc, (float)a1.y * sc);
  o.w = pk2((float)a1.z * sc, (float)a1.w * sc);
  *(uint4*)(w + base) = o;
}

// ================= Path A: clean bf16 GEMMs =================
// gateup: C = silu(x*Wg^T) . (x*Wu^T). 256x128, BK=64, 512thr (8w, 4Mx2N).
__global__ __launch_bounds__(512, 2) void gateup_bf16(
    const unsigned short* __restrict__ xb,
    const unsigned short* __restrict__ wg,
    const unsigned short* __restrict__ wu,
    unsigned short* __restrict__ inter)
{
  __shared__ unsigned short As[2 * 256 * 64];   // 64 KB
  __shared__ unsigned short Bgs[2 * 128 * 64];  // 32 KB
  __shared__ unsigned short Bus[2 * 128 * 64];  // 32 KB

  const int tid = threadIdx.x, lane = tid & 63, wid = tid >> 6;
  const int wm = wid >> 1, wn = wid & 1;
  const int p = blockIdx.x;
  const int l = (p & 7) * 224 + (p >> 3);   // XCD-chunked, 1792 blocks
  const int m0 = (l & 15) * 256, n0 = (l >> 4) * 128;
  const int lr = lane & 15, lc = lane >> 4;

  // staging: linear LDS dest, pre-swizzled source col (chunk ^= row&7)
  const int ra   = tid >> 3;                       // 0..63 (+64k per it)
  const int scol = ((tid & 7) ^ (ra & 7)) << 3;    // row&7 invariant mod 64
  const unsigned short* pa  = xb + (long)(m0 + ra) * HDIM + scol;
  const unsigned short* pbg = wg + (long)(n0 + ra) * HDIM + scol;
  const unsigned short* pbu = wu + (long)(n0 + ra) * HDIM + scol;

#define GU_ST(KT, WRP) do {                                                   \
    const long ko_ = (long)(KT) * 64;                                         \
    unsigned short* la_ = (unsigned short*)As  + (WRP) * 16384 + wid * 512;   \
    unsigned short* lg_ = (unsigned short*)Bgs + (WRP) * 8192  + wid * 512;   \
    unsigned short* lu_ = (unsigned short*)Bus + (WRP) * 8192  + wid * 512;   \
    _Pragma("unroll")                                                         \
    for (int it = 0; it < 4; ++it)                                            \
      GLD16(pa + (long)it * 64 * HDIM + ko_, la_ + it * 4096);                \
    _Pragma("unroll")                                                         \
    for (int it = 0; it < 2; ++it) {                                          \
      GLD16(pbg + (long)it * 64 * HDIM + ko_, lg_ + it * 4096);               \
      GLD16(pbu + (long)it * 64 * HDIM + ko_, lu_ + it * 4096);               \
    }                                                                         \
  } while (0)

  f32x4 accg[4][4], accu[4][4];
  const f32x4 zero = {0.f, 0.f, 0.f, 0.f};
#pragma unroll
  for (int i = 0; i < 4; ++i)
#pragma unroll
    for (int j = 0; j < 4; ++j) { accg[i][j] = zero; accu[i][j] = zero; }

  GU_ST(0, 0);
  WAIT_VM0;
  SBAR;

  const int NK = HDIM / 64;
#pragma unroll 1
  for (int kt = 0; kt < NK; ++kt) {
    const int RD = kt & 1, WR = RD ^ 1;
    if (kt + 1 < NK) { GU_ST(kt + 1, WR); }
    SCHB;
    const unsigned short* Ab  = (const unsigned short*)As  + RD * 16384;
    const unsigned short* Bgb = (const unsigned short*)Bgs + RD * 8192;
    const unsigned short* Bub = (const unsigned short*)Bus + RD * 8192;
    __builtin_amdgcn_s_setprio(1);
#pragma unroll
    for (int ks = 0; ks < 2; ++ks) {
      const int soff = (((ks << 2) + lc) ^ (lr & 7)) << 3;
      bf16x8 af[4];
#pragma unroll
      for (int mi = 0; mi < 4; ++mi)
        af[mi] = *(const bf16x8*)&Ab[(wm * 64 + mi * 16 + lr) * 64 + soff];
#pragma unroll
      for (int ni = 0; ni < 4; ++ni) {
        bf16x8 bg = *(const bf16x8*)&Bgb[(wn * 64 + ni * 16 + lr) * 64 + soff];
        bf16x8 bu = *(const bf16x8*)&Bub[(wn * 64 + ni * 16 + lr) * 64 + soff];
#pragma unroll
        for (int mi = 0; mi < 4; ++mi) {
          accg[mi][ni] = __builtin_amdgcn_mfma_f32_16x16x32_bf16(af[mi], bg, accg[mi][ni], 0, 0, 0);
          accu[mi][ni] = __builtin_amdgcn_mfma_f32_16x16x32_bf16(af[mi], bu, accu[mi][ni], 0, 0, 0);
        }
      }
    }
    __builtin_amdgcn_s_setprio(0);
    SCHB;
    WAIT_VM0;   // next tile's loads (issued ~full compute ago)
    SBAR;
  }

  const int r0 = m0 + wm * 64, c0 = n0 + wn * 64;
#pragma unroll
  for (int mi = 0; mi < 4; ++mi)
#pragma unroll
    for (int ni = 0; ni < 4; ++ni)
#pragma unroll
      for (int r = 0; r < 4; ++r) {
        float g = accg[mi][ni][r], u = accu[mi][ni][r];
        float sv = g / (1.f + __expf(-g));
        int row = r0 + mi * 16 + lc * 4 + r;
        int col = c0 + ni * 16 + lr;
        inter[(long)row * IDIM + col] = f2bf(sv * u);
      }
#undef GU_ST
}

// down: out = inter * Wd^T. 256x128, BK=64.
__global__ __launch_bounds__(512, 2) void down_bf16(
    const unsigned short* __restrict__ inter,
    const unsigned short* __restrict__ wd,
    float* __restrict__ out)
{
  __shared__ unsigned short As[2 * 256 * 64];  // 64 KB
  __shared__ unsigned short Bs[2 * 128 * 64];  // 32 KB

  const int tid = threadIdx.x, lane = tid & 63, wid = tid >> 6;
  const int wm = wid >> 1, wn = wid & 1;
  const int p = blockIdx.x;
  const int l = (p & 7) * 64 + (p >> 3);    // 512 blocks
  const int m0 = (l & 15) * 256, n0 = (l >> 4) * 128;
  const int lr = lane & 15, lc = lane >> 4;

  const int ra   = tid >> 3;
  const int scol = ((tid & 7) ^ (ra & 7)) << 3;
  const unsigned short* pa = inter + (long)(m0 + ra) * IDIM + scol;
  const unsigned short* pb = wd + (long)(n0 + ra) * IDIM + scol;

#define DN_ST(KT, WRP) do {                                                   \
    const long ko_ = (long)(KT) * 64;                                         \
    unsigned short* la_ = (unsigned short*)As + (WRP) * 16384 + wid * 512;    \
    unsigned short* lb_ = (unsigned short*)Bs + (WRP) * 8192  + wid * 512;    \
    _Pragma("unroll")                                                         \
    for (int it = 0; it < 4; ++it)                                            \
      GLD16(pa + (long)it * 64 * IDIM + ko_, la_ + it * 4096);                \
    _Pragma("unroll")                                                         \
    for (int it = 0; it < 2; ++it)                                            \
      GLD16(pb + (long)it * 64 * IDIM + ko_, lb_ + it * 4096);                \
  } while (0)

  f32x4 acc[4][4];
  const f32x4 zero = {0.f, 0.f, 0.f, 0.f};
#pragma unroll
  for (int i = 0; i < 4; ++i)
#pragma unroll
    for (int j = 0; j < 4; ++j) acc[i][j] = zero;

  DN_ST(0, 0);
  WAIT_VM0;
  SBAR;

  const int NK = IDIM / 64;   // 224
#pragma unroll 1
  for (int kt = 0; kt < NK; ++kt) {
    const int RD = kt & 1, WR = RD ^ 1;
    if (kt + 1 < NK) { DN_ST(kt + 1, WR); }
    SCHB;
    const unsigned short* Ab = (const unsigned short*)As + RD * 16384;
    const unsigned short* Bb = (const unsigned short*)Bs + RD * 8192;
    __builtin_amdgcn_s_setprio(1);
#pragma unroll
    for (int ks = 0; ks < 2; ++ks) {
      const int soff = (((ks << 2) + lc) ^ (lr & 7)) << 3;
      bf16x8 af[4], bfr[4];
#pragma unroll
      for (int mi = 0; mi < 4; ++mi)
        af[mi] = *(const bf16x8*)&Ab[(wm * 64 + mi * 16 + lr) * 64 + soff];
#pragma unroll
      for (int ni = 0; ni < 4; ++ni)
        bfr[ni] = *(const bf16x8*)&Bb[(wn * 64 + ni * 16 + lr) * 64 + soff];
#pragma unroll
      for (int ni = 0; ni < 4; ++ni)
#pragma unroll
        for (int mi = 0; mi < 4; ++mi)
          acc[mi][ni] = __builtin_amdgcn_mfma_f32_16x16x32_bf16(af[mi], bfr[ni], acc[mi][ni], 0, 0, 0);
    }
    __builtin_amdgcn_s_setprio(0);
    SCHB;
    WAIT_VM0;
    SBAR;
  }

  const int r0 = m0 + wm * 64, c0 = n0 + wn * 64;
#pragma unroll
  for (int mi = 0; mi < 4; ++mi)
#pragma unroll
    for (int ni = 0; ni < 4; ++ni)
#pragma unroll
      for (int r = 0; r < 4; ++r) {
        int row = r0 + mi * 16 + lc * 4 + r;
        int col = c0 + ni * 16 + lr;
        out[(long)row * HDIM + col] = acc[mi][ni][r];
      }
#undef DN_ST
}

// ================= Path B fallback: inline-dequant (R4 structure) =================
__global__ __launch_bounds__(512, 2) void gu_inline(
    const unsigned short* __restrict__ xb,
    const int* __restrict__ gq, const float* __restrict__ gs,
    const int* __restrict__ uq, const float* __restrict__ us,
    unsigned short* __restrict__ inter)
{
  __shared__ unsigned short As[2 * 256 * 64];
  __shared__ unsigned short Bg[2 * 128 * 64];
  __shared__ unsigned short Bu[2 * 128 * 64];
  const int tid = threadIdx.x, lane = tid & 63, wid = tid >> 6;
  const int wm = wid >> 1, wn = wid & 1;
  const int p = blockIdx.x;
  const int l = (p & 7) * 224 + (p >> 3);
  const int m0 = (l & 15) * 256, n0 = (l >> 4) * 128;
  const int lr = lane & 15, lc = lane >> 4;
  const int ra = tid >> 3;
  const int scol = ((tid & 7) ^ (ra & 7)) << 3;
  const unsigned short* pa = xb + (long)(m0 + ra) * HDIM + scol;
  unsigned short* lbase = (unsigned short*)As + wid * 512;
  const int rb = tid >> 3, cb = (tid & 7) << 3;
  const int swz = ((tid & 7) ^ (rb & 7)) << 3;
  const int sidx0 = rb * 64 + swz, sidx1 = (64 + rb) * 64 + swz;
  const int* pg0 = gq + (long)(n0 + rb) * HDIM + cb;
  const int* pg1 = pg0 + 64 * HDIM;
  const int* pu0 = uq + (long)(n0 + rb) * HDIM + cb;
  const int* pu1 = pu0 + 64 * HDIM;
  const float* psg0 = gs + (n0 + rb) * (HDIM / GRP);
  const float* psg1 = psg0 + 64 * (HDIM / GRP);
  const float* psu0 = us + (n0 + rb) * (HDIM / GRP);
  const float* psu1 = psu0 + 64 * (HDIM / GRP);
  int4 q[8]; float sc[4];
#define GI_A(KTA, WRP) do {                                                   \
    const unsigned short* g_ = pa + (KTA) * 64;                               \
    unsigned short* l_ = lbase + (WRP) * 16384;                               \
    _Pragma("unroll")                                                         \
    for (int it = 0; it < 4; ++it)                                            \
      GLD16(g_ + (long)it * 64 * HDIM, l_ + it * 4096);                       \
  } while (0)
#define GI_LB(KT) do { const int kk_ = (KT) << 6;                             \
    q[0] = *(const int4*)(pg0 + kk_); q[1] = *(const int4*)(pg0 + kk_ + 4);   \
    q[2] = *(const int4*)(pg1 + kk_); q[3] = *(const int4*)(pg1 + kk_ + 4);   \
    q[4] = *(const int4*)(pu0 + kk_); q[5] = *(const int4*)(pu0 + kk_ + 4);   \
    q[6] = *(const int4*)(pu1 + kk_); q[7] = *(const int4*)(pu1 + kk_ + 4);   \
    const int so_ = (KT) >> 1;                                                \
    sc[0] = psg0[so_]; sc[1] = psg1[so_]; sc[2] = psu0[so_]; sc[3] = psu1[so_]; \
  } while (0)
#define GI_WB(WRP) do {                                                       \
    unsigned short* Bg_ = (unsigned short*)Bg + (WRP) * 8192;                 \
    unsigned short* Bu_ = (unsigned short*)Bu + (WRP) * 8192;                 \
    uint4 w_;                                                                 \
    w_.x = pk2((float)q[0].x * sc[0], (float)q[0].y * sc[0]);                 \
    w_.y = pk2((float)q[0].z * sc[0], (float)q[0].w * sc[0]);                 \
    w_.z = pk2((float)q[1].x * sc[0], (float)q[1].y * sc[0]);                 \
    w_.w = pk2((float)q[1].z * sc[0], (float)q[1].w * sc[0]);                 \
    *(uint4*)&Bg_[sidx0] = w_;                                                \
    w_.x = pk2((float)q[2].x * sc[1], (float)q[2].y * sc[1]);                 \
    w_.y = pk2((float)q[2].z * sc[1], (float)q[2].w * sc[1]);                 \
    w_.z = pk2((float)q[3].x * sc[1], (float)q[3].y * sc[1]);                 \
    w_.w = pk2((float)q[3].z * sc[1], (float)q[3].w * sc[1]);                 \
    *(uint4*)&Bg_[sidx1] = w_;                                                \
    w_.x = pk2((float)q[4].x * sc[2], (float)q[4].y * sc[2]);                 \
    w_.y = pk2((float)q[4].z * sc[2], (float)q[4].w * sc[2]);                 \
    w_.z = pk2((float)q[5].x * sc[2], (float)q[5].y * sc[2]);                 \
    w_.w = pk2((float)q[5].z * sc[2], (float)q[5].w * sc[2]);                 \
    *(uint4*)&Bu_[sidx0] = w_;                                                \
    w_.x = pk2((float)q[6].x * sc[3], (float)q[6].y * sc[3]);                 \
    w_.y = pk2((float)q[6].z * sc[3], (float)q[6].w * sc[3]);                 \
    w_.z = pk2((float)q[7].x * sc[3], (float)q[7].y * sc[3]);                 \
    w_.w = pk2((float)q[7].z * sc[3], (float)q[7].w * sc[3]);                 \
    *(uint4*)&Bu_[sidx1] = w_;                                                \
  } while (0)
  f32x4 accg[4][4], accu[4][4];
  const f32x4 zero = {0.f, 0.f, 0.f, 0.f};
#pragma unroll
  for (int i = 0; i < 4; ++i)
#pragma unroll
    for (int j = 0; j < 4; ++j) { accg[i][j] = zero; accu[i][j] = zero; }
  GI_A(0, 0); GI_LB(0); GI_WB(0);
  __syncthreads();
  const int NK = HDIM / 64;
#pragma unroll 1
  for (int kt = 0; kt < NK; ++kt) {
    const int RD = kt & 1, WR = RD ^ 1;
    const int ktn = (kt + 1 < NK) ? kt + 1 : kt;
    GI_A(ktn, WR);
    SCHB;
    GI_LB(ktn);
    SCHB;
    {
      const unsigned short* Ab  = (const unsigned short*)As + RD * 16384;
      const unsigned short* Bgb = (const unsigned short*)Bg + RD * 8192;
      const unsigned short* Bub = (const unsigned short*)Bu + RD * 8192;
      __builtin_amdgcn_s_setprio(1);
#pragma unroll
      for (int ks = 0; ks < 2; ++ks) {
        const int soff = (((ks << 2) + lc) ^ (lr & 7)) << 3;
        bf16x8 af[4];
#pragma unroll
        for (int mi = 0; mi < 4; ++mi)
          af[mi] = *(const bf16x8*)&Ab[(wm * 64 + mi * 16 + lr) * 64 + soff];
#pragma unroll
        for (int ni = 0; ni < 4; ++ni) {
          bf16x8 bg = *(const bf16x8*)&Bgb[(wn * 64 + ni * 16 + lr) * 64 + soff];
          bf16x8 bu = *(const bf16x8*)&Bub[(wn * 64 + ni * 16 + lr) * 64 + soff];
#pragma unroll
          for (int mi = 0; mi < 4; ++mi) {
            accg[mi][ni] = __builtin_amdgcn_mfma_f32_16x16x32_bf16(af[mi], bg, accg[mi][ni], 0, 0, 0);
            accu[mi][ni] = __builtin_amdgcn_mfma_f32_16x16x32_bf16(af[mi], bu, accu[mi][ni], 0, 0, 0);
          }
        }
      }
      __builtin_amdgcn_s_setprio(0);
    }
    SCHB;
    GI_WB(WR);
    __syncthreads();
  }
  const int r0 = m0 + wm * 64, c0 = n0 + wn * 64;
#pragma unroll
  for (int mi = 0; mi < 4; ++mi)
#pragma unroll
    for (int ni = 0; ni < 4; ++ni)
#pragma unroll
      for (int r = 0; r < 4; ++r) {
        float g = accg[mi][ni][r], u = accu[mi][ni][r];
        float sv = g / (1.f + __expf(-g));
        int row = r0 + mi * 16 + lc * 4 + r;
        int col = c0 + ni * 16 + lr;
        inter[(long)row * IDIM + col] = f2bf(sv * u);
      }
#undef GI_A
#undef GI_LB
#undef GI_WB
}

__global__ __launch_bounds__(512, 2) void dn_inline(
    const unsigned short* __restrict__ inter,
    const int* __restrict__ dq, const float* __restrict__ dsc,
    float* __restrict__ out)
{
  __shared__ unsigned short As[2 * 256 * 64];
  __shared__ unsigned short Bs[2 * 128 * 64];
  const int tid = threadIdx.x, lane = tid & 63, wid = tid >> 6;
  const int wm = wid >> 1, wn = wid & 1;
  const int p = blockIdx.x;
  const int l = (p & 7) * 64 + (p >> 3);
  const int m0 = (l & 15) * 256, n0 = (l >> 4) * 128;
  const int lr = lane & 15, lc = lane >> 4;
  const int ra = tid >> 3;
  const int scol = ((tid & 7) ^ (ra & 7)) << 3;
  const unsigned short* pa = inter + (long)(m0 + ra) * IDIM + scol;
  unsigned short* lbase = (unsigned short*)As + wid * 512;
  const int rb = tid >> 3, cb = (tid & 7) << 3;
  const int swz = ((tid & 7) ^ (rb & 7)) << 3;
  const int sidx0 = rb * 64 + swz, sidx1 = (64 + rb) * 64 + swz;
  const int* pd0 = dq + (long)(n0 + rb) * IDIM + cb;
  const int* pd1 = pd0 + 64 * IDIM;
  const float* ps0 = dsc + (n0 + rb) * (IDIM / GRP);
  const float* ps1 = ps0 + 64 * (IDIM / GRP);
  int4 q[4]; float sc[2];
#define DI_A(KTA, WRP) do {                                                   \
    const unsigned short* g_ = pa + (KTA) * 64;                               \
    unsigned short* l_ = lbase + (WRP) * 16384;                               \
    _Pragma("unroll")                                                         \
    for (int it = 0; it < 4; ++it)                                            \
      GLD16(g_ + (long)it * 64 * IDIM, l_ + it * 4096);                       \
  } while (0)
#define DI_LB(KT) do { const int kk_ = (KT) << 6;                             \
    q[0] = *(const int4*)(pd0 + kk_); q[1] = *(const int4*)(pd0 + kk_ + 4);   \
    q[2] = *(const int4*)(pd1 + kk_); q[3] = *(const int4*)(pd1 + kk_ + 4);   \
    const int so_ = (KT) >> 1;                                                \
    sc[0] = ps0[so_]; sc[1] = ps1[so_]; } while (0)
#define DI_WB(WRP) do {                                                       \
    unsigned short* B_ = (unsigned short*)Bs + (WRP) * 8192;                  \
    uint4 w_;                                                                 \
    w_.x = pk2((float)q[0].x * sc[0], (float)q[0].y * sc[0]);                 \
    w_.y = pk2((float)q[0].z * sc[0], (float)q[0].w * sc[0]);                 \
    w_.z = pk2((float)q[1].x * sc[0], (float)q[1].y * sc[0]);                 \
    w_.w = pk2((float)q[1].z * sc[0], (float)q[1].w * sc[0]);                 \
    *(uint4*)&B_[sidx0] = w_;                                                 \
    w_.x = pk2((float)q[2].x * sc[1], (float)q[2].y * sc[1]);                 \
    w_.y = pk2((float)q[2].z * sc[1], (float)q[2].w * sc[1]);                 \
    w_.z = pk2((float)q[3].x * sc[1], (float)q[3].y * sc[1]);                 \
    w_.w = pk2((float)q[3].z * sc[1], (float)q[3].w * sc[1]);                 \
    *(uint4*)&B_[sidx1] = w_;                                                 \
  } while (0)
  f32x4 acc[4][4];
  const f32x4 zero = {0.f, 0.f, 0.f, 0.f};
#pragma unroll
  for (int i = 0; i < 4; ++i)
#pragma unroll
    for (int j = 0; j < 4; ++j) acc[i][j] = zero;
  DI_A(0, 0); DI_LB(0); DI_WB(0);
  __syncthreads();
  const int NK = IDIM / 64;
#pragma unroll 1
  for (int kt = 0; kt < NK; ++kt) {
    const int RD = kt & 1, WR = RD ^ 1;
    const int ktn = (kt + 1 < NK) ? kt + 1 : kt;
    DI_A(ktn, WR);
    SCHB;
    DI_LB(ktn);
    SCHB;
    {
      const unsigned short* Ab = (const unsigned short*)As + RD * 16384;
      const unsigned short* Bb = (const unsigned short*)Bs + RD * 8192;
      __builtin_amdgcn_s_setprio(1);
#pragma unroll
      for (int ks = 0; ks < 2; ++ks) {
        const int soff = (((ks << 2) + lc) ^ (lr & 7)) << 3;
        bf16x8 af[4], bfr[4];
#pragma unroll
        for (int mi = 0; mi < 4; ++mi)
          af[mi] = *(const bf16x8*)&Ab[(wm * 64 + mi * 16 + lr) * 64 + soff];
#pragma unroll
        for (int ni = 0; ni < 4; ++ni)
          bfr[ni] = *(const bf16x8*)&Bb[(wn * 64 + ni * 16 + lr) * 64 + soff];
#pragma unroll
        for (int ni = 0; ni < 4; ++ni)
#pragma unroll
          for (int mi = 0; mi < 4; ++mi)
            acc[mi][ni] = __builtin_amdgcn_mfma_f32_16x16x32_bf16(af[mi], bfr[ni], acc[mi][ni], 0, 0, 0);
      }
      __builtin_amdgcn_s_setprio(0);
    }
    SCHB;
    DI_WB(WR);
    __syncthreads();
  }
  const int r0 = m0 + wm * 64, c0 = n0 + wn * 64;
#pragma unroll
  for (int mi = 0; mi < 4; ++mi)
#pragma unroll
    for (int ni = 0; ni < 4; ++ni)
#pragma unroll
      for (int r = 0; r < 4; ++r) {
        int row = r0 + mi * 16 + lc * 4 + r;
        int col = c0 + ni * 16 + lr;
        out[(long)row * HDIM + col] = acc[mi][ni][r];
      }
#undef DI_A
#undef DI_LB
#undef DI_WB
}

extern "C" void kernel_launch(void* const* d_in, const int* in_sizes, int n_in,
                              void* d_out, int out_size, void* d_ws, size_t ws_size,
                              hipStream_t stream) {
  const float* x   = (const float*)d_in[0];
  const int*   gq  = (const int*)d_in[1];
  const float* gsc = (const float*)d_in[2];
  const int*   uq  = (const int*)d_in[3];
  const float* usc = (const float*)d_in[4];
  const int*   dq  = (const int*)d_in[5];
  const float* dsc = (const float*)d_in[6];
  float* out = (float*)d_out;

  unsigned short* xb    = (unsigned short*)d_ws;                    // 32 MiB
  unsigned short* inter = xb + (size_t)MTOK * HDIM;                 // 112 MiB
  unsigned short* wgb   = inter + (size_t)MTOK * IDIM;              // 112 MiB
  unsigned short* wub   = wgb + (size_t)IDIM * HDIM;                // 112 MiB
  const size_t needed = ((size_t)MTOK * HDIM + (size_t)MTOK * IDIM +
                         2 * (size_t)IDIM * HDIM) * 2;

  hipLaunchKernelGGL(cvt_x_kernel, dim3(2048), dim3(256), 0, stream, x, xb);

  if (ws_size >= needed) {
    // Path A: pre-dequantized bf16 weights, clean GEMMs.
    hipLaunchKernelGGL(deq_kernel, dim3(HDIM / 2048, IDIM), dim3(256), 0, stream,
                       gq, gsc, wgb, HDIM);
    hipLaunchKernelGGL(deq_kernel, dim3(HDIM / 2048, IDIM), dim3(256), 0, stream,
                       uq, usc, wub, HDIM);
    hipLaunchKernelGGL(gateup_bf16, dim3(1792), dim3(512), 0, stream,
                       xb, wgb, wub, inter);
    // down weights reuse the (now free) gate-weight region
    hipLaunchKernelGGL(deq_kernel, dim3(IDIM / 2048, HDIM), dim3(256), 0, stream,
                       dq, dsc, wgb, IDIM);
    hipLaunchKernelGGL(down_bf16, dim3(512), dim3(512), 0, stream,
                       inter, wgb, out);
  } else {
    // Path B: inline dequant (R4 structure).
    hipLaunchKernelGGL(gu_inline, dim3(1792), dim3(512), 0, stream,
                       xb, gq, gsc, uq, usc, inter);
    hipLaunchKernelGGL(dn_inline, dim3(512), dim3(512), 0, stream,
                       inter, dq, dsc, out);
  }
}

// Round 9
// 1588.849 us; speedup vs baseline: 6.2301x; 1.2286x over previous
//
#include <hip/hip_runtime.h>
#include <hip/hip_bf16.h>

// LlamaMLPInfer: SwiGLU MLP with group(128)-dequantized int4 weights.
// R9: pre-dequant (R8) + counted-vmcnt phased K-loops (T3+T4+T5):
//  gateup: A triple-buffer (2-tile lead), Bg/Bu double (1-tile lead),
//          head wait vmcnt(4), 4 phases/tile, LDS 160KB.
//  down:   A+B triple-buffer (2-tile lead), head wait vmcnt(6),
//          2 phases/tile, LDS 144KB.
// No vmcnt(0) anywhere in the main loops; no stage-into-live-buffer hazards.

#define HDIM 4096
#define IDIM 14336
#define MTOK 4096
#define GRP 128

typedef __attribute__((ext_vector_type(8))) short bf16x8;
typedef __attribute__((ext_vector_type(4))) float f32x4;
typedef __attribute__((ext_vector_type(4))) unsigned short u16x4;

#define WAIT_LGKM0 asm volatile("s_waitcnt lgkmcnt(0)" ::: "memory")
#define WAIT_VM(N) asm volatile("s_waitcnt vmcnt(" #N ")" ::: "memory")
#define SBAR       __builtin_amdgcn_s_barrier()
#define SCHB       __builtin_amdgcn_sched_barrier(0)

__device__ __forceinline__ unsigned short f2bf(float f) {
  union { float f; unsigned int u; } v; v.f = f;
  return (unsigned short)((v.u + 0x7fffu + ((v.u >> 16) & 1u)) >> 16);  // RNE
}
__device__ __forceinline__ unsigned pk2(float a, float b) {
  union { float f; unsigned u; } ua, ub; ua.f = a; ub.f = b;
  return __builtin_amdgcn_perm(ub.u, ua.u, 0x07060302u);
}

#define GLD16(G, L)                                                           \
  __builtin_amdgcn_global_load_lds(                                           \
      (const __attribute__((address_space(1))) unsigned int*)(G),             \
      (__attribute__((address_space(3))) unsigned int*)(L), 16, 0, 0)

// ---------------- x fp32 -> bf16 ----------------
__global__ __launch_bounds__(256) void cvt_x_kernel(const float* __restrict__ x,
                                                    unsigned short* __restrict__ xb) {
  const int n = MTOK * HDIM;
  const int stride = gridDim.x * 256 * 4;
  for (int i = (blockIdx.x * 256 + threadIdx.x) * 4; i < n; i += stride) {
    float4 v = *reinterpret_cast<const float4*>(x + i);
    u16x4 o;
    o[0] = f2bf(v.x); o[1] = f2bf(v.y); o[2] = f2bf(v.z); o[3] = f2bf(v.w);
    *reinterpret_cast<u16x4*>(xb + i) = o;
  }
}

// ---------------- weight dequant ----------------
__global__ __launch_bounds__(256) void deq_kernel(const int* __restrict__ q,
                                                  const float* __restrict__ s,
                                                  unsigned short* __restrict__ w,
                                                  int In) {
  const int row  = blockIdx.y;
  const int col0 = blockIdx.x * 2048 + threadIdx.x * 8;
  const long base = (long)row * In + col0;
  const float sc = s[row * (In / GRP) + (col0 >> 7)];
  const int4* p = (const int4*)(q + base);
  int4 a0 = p[0], a1 = p[1];
  uint4 o;
  o.x = pk2((float)a0.x * sc, (float)a0.y * sc);
  o.y = pk2((float)a0.z * sc, (float)a0.w * sc);
  o.z = pk2((float)a1.x * sc, (float)a1.y * sc);
  o.w = pk2((float)a1.z * sc, (float)a1.w * sc);
  *(uint4*)(w + base) = o;
}

// ================= fused gate+up GEMM =================
// 256x128, BK=64, 512 thr (8 waves, 4Mx2N). A 3-buf, B 2-buf. vmcnt(4) head.
__global__ __launch_bounds__(512, 2) void gateup_bf16(
    const unsigned short* __restrict__ xb,
    const unsigned short* __restrict__ wg,
    const unsigned short* __restrict__ wu,
    unsigned short* __restrict__ inter)
{
  __shared__ unsigned short As[3 * 256 * 64];   // 96 KB
  __shared__ unsigned short Bgs[2 * 128 * 64];  // 32 KB
  __shared__ unsigned short Bus[2 * 128 * 64];  // 32 KB

  const int tid = threadIdx.x, lane = tid & 63, wid = tid >> 6;
  const int wm = wid >> 1, wn = wid & 1;
  const int p = blockIdx.x;
  const int l = (p & 7) * 224 + (p >> 3);   // XCD-chunked, 1792 blocks
  const int m0 = (l & 15) * 256, n0 = (l >> 4) * 128;
  const int lr = lane & 15, lc = lane >> 4;

  const int ra   = tid >> 3;
  const int scol = ((tid & 7) ^ (ra & 7)) << 3;
  const unsigned short* pa  = xb + (long)(m0 + ra) * HDIM + scol;
  const unsigned short* pbg = wg + (long)(n0 + ra) * HDIM + scol;
  const unsigned short* pbu = wu + (long)(n0 + ra) * HDIM + scol;

#define A1(KT, BUF, IT)                                                       \
  GLD16(pa + (long)(IT) * 64 * HDIM + (long)(KT) * 64,                        \
        (unsigned short*)As + (BUF) * 16384 + (IT) * 4096 + wid * 512)
#define BG1(KT, BUF, IT)                                                      \
  GLD16(pbg + (long)(IT) * 64 * HDIM + (long)(KT) * 64,                       \
        (unsigned short*)Bgs + (BUF) * 8192 + (IT) * 4096 + wid * 512)
#define BU1(KT, BUF, IT)                                                      \
  GLD16(pbu + (long)(IT) * 64 * HDIM + (long)(KT) * 64,                       \
        (unsigned short*)Bus + (BUF) * 8192 + (IT) * 4096 + wid * 512)

  f32x4 accg[4][4], accu[4][4];
  const f32x4 zero = {0.f, 0.f, 0.f, 0.f};
#pragma unroll
  for (int i = 0; i < 4; ++i)
#pragma unroll
    for (int j = 0; j < 4; ++j) { accg[i][j] = zero; accu[i][j] = zero; }

  // prologue: in-flight order must be [A(0)x4, B(0)x4, A(1)x4]
  A1(0, 0, 0); A1(0, 0, 1); A1(0, 0, 2); A1(0, 0, 3);
  SCHB;
  BG1(0, 0, 0); BG1(0, 0, 1); BU1(0, 0, 0); BU1(0, 0, 1);
  SCHB;
  A1(1, 1, 0); A1(1, 1, 1); A1(1, 1, 2); A1(1, 1, 3);
  SCHB;

  const int NK = HDIM / 64;   // 64
#pragma unroll 1
  for (int kt = 0; kt < NK; ++kt) {
    // head: retire A(kt)+B(kt) (8 oldest of 12); A(kt+1) stays in flight
    WAIT_VM(4);
    SCHB;
    SBAR;
    SCHB;
    const unsigned short* Ab  = (const unsigned short*)As  + (kt % 3) * 16384;
    const unsigned short* Bgb = (const unsigned short*)Bgs + (kt & 1) * 8192;
    const unsigned short* Bub = (const unsigned short*)Bus + (kt & 1) * 8192;
    const int ktb = (kt + 1 < NK) ? kt + 1 : NK - 1;   // B stage src (1-lead)
    const int wrb = (kt + 1) & 1;
    const int kta = (kt + 2 < NK) ? kt + 2 : NK - 1;   // A stage src (2-lead)
    const int wra = (kt + 2) % 3;
    const int soff0 = (lc ^ (lr & 7)) << 3;
    const int soff1 = ((4 + lc) ^ (lr & 7)) << 3;
    bf16x8 af[4], bfr[4];

    // ---- ph0: gate, ks0 ----
#pragma unroll
    for (int mi = 0; mi < 4; ++mi)
      af[mi] = *(const bf16x8*)&Ab[(wm * 64 + mi * 16 + lr) * 64 + soff0];
#pragma unroll
    for (int ni = 0; ni < 4; ++ni)
      bfr[ni] = *(const bf16x8*)&Bgb[(wn * 64 + ni * 16 + lr) * 64 + soff0];
    BG1(ktb, wrb, 0); BG1(ktb, wrb, 1);
    SCHB; SBAR; WAIT_LGKM0; SCHB;
    __builtin_amdgcn_s_setprio(1);
#pragma unroll
    for (int ni = 0; ni < 4; ++ni)
#pragma unroll
      for (int mi = 0; mi < 4; ++mi)
        accg[mi][ni] = __builtin_amdgcn_mfma_f32_16x16x32_bf16(af[mi], bfr[ni], accg[mi][ni], 0, 0, 0);
    __builtin_amdgcn_s_setprio(0);
    SBAR; SCHB;

    // ---- ph1: up, ks0 (af reused) ----
#pragma unroll
    for (int ni = 0; ni < 4; ++ni)
      bfr[ni] = *(const bf16x8*)&Bub[(wn * 64 + ni * 16 + lr) * 64 + soff0];
    BU1(ktb, wrb, 0); BU1(ktb, wrb, 1);
    SCHB; SBAR; WAIT_LGKM0; SCHB;
    __builtin_amdgcn_s_setprio(1);
#pragma unroll
    for (int ni = 0; ni < 4; ++ni)
#pragma unroll
      for (int mi = 0; mi < 4; ++mi)
        accu[mi][ni] = __builtin_amdgcn_mfma_f32_16x16x32_bf16(af[mi], bfr[ni], accu[mi][ni], 0, 0, 0);
    __builtin_amdgcn_s_setprio(0);
    SBAR; SCHB;

    // ---- ph2: gate, ks1 ----
#pragma unroll
    for (int mi = 0; mi < 4; ++mi)
      af[mi] = *(const bf16x8*)&Ab[(wm * 64 + mi * 16 + lr) * 64 + soff1];
#pragma unroll
    for (int ni = 0; ni < 4; ++ni)
      bfr[ni] = *(const bf16x8*)&Bgb[(wn * 64 + ni * 16 + lr) * 64 + soff1];
    A1(kta, wra, 0); A1(kta, wra, 1);
    SCHB; SBAR; WAIT_LGKM0; SCHB;
    __builtin_amdgcn_s_setprio(1);
#pragma unroll
    for (int ni = 0; ni < 4; ++ni)
#pragma unroll
      for (int mi = 0; mi < 4; ++mi)
        accg[mi][ni] = __builtin_amdgcn_mfma_f32_16x16x32_bf16(af[mi], bfr[ni], accg[mi][ni], 0, 0, 0);
    __builtin_amdgcn_s_setprio(0);
    SBAR; SCHB;

    // ---- ph3: up, ks1 ----
#pragma unroll
    for (int ni = 0; ni < 4; ++ni)
      bfr[ni] = *(const bf16x8*)&Bub[(wn * 64 + ni * 16 + lr) * 64 + soff1];
    A1(kta, wra, 2); A1(kta, wra, 3);
    SCHB; SBAR; WAIT_LGKM0; SCHB;
    __builtin_amdgcn_s_setprio(1);
#pragma unroll
    for (int ni = 0; ni < 4; ++ni)
#pragma unroll
      for (int mi = 0; mi < 4; ++mi)
        accu[mi][ni] = __builtin_amdgcn_mfma_f32_16x16x32_bf16(af[mi], bfr[ni], accu[mi][ni], 0, 0, 0);
    __builtin_amdgcn_s_setprio(0);
    SCHB;   // tile-trailing barrier provided by next head SBAR
  }

  // ---- epilogue: silu(g)*u -> bf16 ----
  const int r0 = m0 + wm * 64, c0 = n0 + wn * 64;
#pragma unroll
  for (int mi = 0; mi < 4; ++mi)
#pragma unroll
    for (int ni = 0; ni < 4; ++ni)
#pragma unroll
      for (int r = 0; r < 4; ++r) {
        float g = accg[mi][ni][r], u = accu[mi][ni][r];
        float sv = g / (1.f + __expf(-g));
        int row = r0 + mi * 16 + lc * 4 + r;
        int col = c0 + ni * 16 + lr;
        inter[(long)row * IDIM + col] = f2bf(sv * u);
      }
#undef A1
#undef BG1
#undef BU1
}

// ================= down GEMM =================
// 256x128, BK=64. A+B 3-buf (2-lead). vmcnt(6) head. 2 phases/tile.
__global__ __launch_bounds__(512, 2) void down_bf16(
    const unsigned short* __restrict__ inter,
    const unsigned short* __restrict__ wd,
    float* __restrict__ out)
{
  __shared__ unsigned short As[3 * 256 * 64];  // 96 KB
  __shared__ unsigned short Bs[3 * 128 * 64];  // 48 KB

  const int tid = threadIdx.x, lane = tid & 63, wid = tid >> 6;
  const int wm = wid >> 1, wn = wid & 1;
  const int p = blockIdx.x;
  const int l = (p & 7) * 64 + (p >> 3);    // 512 blocks
  const int m0 = (l & 15) * 256, n0 = (l >> 4) * 128;
  const int lr = lane & 15, lc = lane >> 4;

  const int ra   = tid >> 3;
  const int scol = ((tid & 7) ^ (ra & 7)) << 3;
  const unsigned short* pa = inter + (long)(m0 + ra) * IDIM + scol;
  const unsigned short* pb = wd + (long)(n0 + ra) * IDIM + scol;

#define DA1(KT, BUF, IT)                                                      \
  GLD16(pa + (long)(IT) * 64 * IDIM + (long)(KT) * 64,                        \
        (unsigned short*)As + (BUF) * 16384 + (IT) * 4096 + wid * 512)
#define DB1(KT, BUF, IT)                                                      \
  GLD16(pb + (long)(IT) * 64 * IDIM + (long)(KT) * 64,                        \
        (unsigned short*)Bs + (BUF) * 8192 + (IT) * 4096 + wid * 512)

  f32x4 acc[4][4];
  const f32x4 zero = {0.f, 0.f, 0.f, 0.f};
#pragma unroll
  for (int i = 0; i < 4; ++i)
#pragma unroll
    for (int j = 0; j < 4; ++j) acc[i][j] = zero;

  // prologue: order [B(0)2, A(0)4, B(1)2, A(1)4]
  DB1(0, 0, 0); DB1(0, 0, 1);
  SCHB;
  DA1(0, 0, 0); DA1(0, 0, 1); DA1(0, 0, 2); DA1(0, 0, 3);
  SCHB;
  DB1(1, 1, 0); DB1(1, 1, 1);
  SCHB;
  DA1(1, 1, 0); DA1(1, 1, 1); DA1(1, 1, 2); DA1(1, 1, 3);
  SCHB;

  const int NK = IDIM / 64;   // 224
#pragma unroll 1
  for (int kt = 0; kt < NK; ++kt) {
    WAIT_VM(6);     // retire tile kt's 6; kt+1's stay in flight
    SCHB;
    SBAR;
    SCHB;
    const unsigned short* Ab = (const unsigned short*)As + (kt % 3) * 16384;
    const unsigned short* Bb = (const unsigned short*)Bs + (kt % 3) * 8192;
    const int ktc = (kt + 2 < NK) ? kt + 2 : NK - 1;
    const int wrc = (kt + 2) % 3;
    const int soff0 = (lc ^ (lr & 7)) << 3;
    const int soff1 = ((4 + lc) ^ (lr & 7)) << 3;
    bf16x8 af[4], bfr[4];

    // ---- ph0: ks0 ----
#pragma unroll
    for (int mi = 0; mi < 4; ++mi)
      af[mi] = *(const bf16x8*)&Ab[(wm * 64 + mi * 16 + lr) * 64 + soff0];
#pragma unroll
    for (int ni = 0; ni < 4; ++ni)
      bfr[ni] = *(const bf16x8*)&Bb[(wn * 64 + ni * 16 + lr) * 64 + soff0];
    DB1(ktc, wrc, 0); DB1(ktc, wrc, 1); DA1(ktc, wrc, 0);
    SCHB; SBAR; WAIT_LGKM0; SCHB;
    __builtin_amdgcn_s_setprio(1);
#pragma unroll
    for (int ni = 0; ni < 4; ++ni)
#pragma unroll
      for (int mi = 0; mi < 4; ++mi)
        acc[mi][ni] = __builtin_amdgcn_mfma_f32_16x16x32_bf16(af[mi], bfr[ni], acc[mi][ni], 0, 0, 0);
    __builtin_amdgcn_s_setprio(0);
    SBAR; SCHB;

    // ---- ph1: ks1 ----
#pragma unroll
    for (int mi = 0; mi < 4; ++mi)
      af[mi] = *(const bf16x8*)&Ab[(wm * 64 + mi * 16 + lr) * 64 + soff1];
#pragma unroll
    for (int ni = 0; ni < 4; ++ni)
      bfr[ni] = *(const bf16x8*)&Bb[(wn * 64 + ni * 16 + lr) * 64 + soff1];
    DA1(ktc, wrc, 1); DA1(ktc, wrc, 2); DA1(ktc, wrc, 3);
    SCHB; SBAR; WAIT_LGKM0; SCHB;
    __builtin_amdgcn_s_setprio(1);
#pragma unroll
    for (int ni = 0; ni < 4; ++ni)
#pragma unroll
      for (int mi = 0; mi < 4; ++mi)
        acc[mi][ni] = __builtin_amdgcn_mfma_f32_16x16x32_bf16(af[mi], bfr[ni], acc[mi][ni], 0, 0, 0);
    __builtin_amdgcn_s_setprio(0);
    SCHB;   // next head SBAR closes the tile
  }

  const int r0 = m0 + wm * 64, c0 = n0 + wn * 64;
#pragma unroll
  for (int mi = 0; mi < 4; ++mi)
#pragma unroll
    for (int ni = 0; ni < 4; ++ni)
#pragma unroll
      for (int r = 0; r < 4; ++r) {
        int row = r0 + mi * 16 + lc * 4 + r;
        int col = c0 + ni * 16 + lr;
        out[(long)row * HDIM + col] = acc[mi][ni][r];
      }
#undef DA1
#undef DB1
}

extern "C" void kernel_launch(void* const* d_in, const int* in_sizes, int n_in,
                              void* d_out, int out_size, void* d_ws, size_t ws_size,
                              hipStream_t stream) {
  const float* x   = (const float*)d_in[0];
  const int*   gq  = (const int*)d_in[1];
  const float* gsc = (const float*)d_in[2];
  const int*   uq  = (const int*)d_in[3];
  const float* usc = (const float*)d_in[4];
  const int*   dq  = (const int*)d_in[5];
  const float* dsc = (const float*)d_in[6];
  float* out = (float*)d_out;

  unsigned short* xb    = (unsigned short*)d_ws;                    // 32 MiB
  unsigned short* inter = xb + (size_t)MTOK * HDIM;                 // 112 MiB
  unsigned short* wgb   = inter + (size_t)MTOK * IDIM;              // 112 MiB
  unsigned short* wub   = wgb + (size_t)IDIM * HDIM;                // 112 MiB

  hipLaunchKernelGGL(cvt_x_kernel, dim3(2048), dim3(256), 0, stream, x, xb);
  hipLaunchKernelGGL(deq_kernel, dim3(HDIM / 2048, IDIM), dim3(256), 0, stream,
                     gq, gsc, wgb, HDIM);
  hipLaunchKernelGGL(deq_kernel, dim3(HDIM / 2048, IDIM), dim3(256), 0, stream,
                     uq, usc, wub, HDIM);
  hipLaunchKernelGGL(gateup_bf16, dim3(1792), dim3(512), 0, stream,
                     xb, wgb, wub, inter);
  // down weights reuse the (now free) gate-weight region
  hipLaunchKernelGGL(deq_kernel, dim3(IDIM / 2048, HDIM), dim3(256), 0, stream,
                     dq, dsc, wgb, IDIM);
  hipLaunchKernelGGL(down_bf16, dim3(512), dim3(512), 0, stream,
                     inter, wgb, out);
}

// Round 10
// 1552.954 us; speedup vs baseline: 6.3741x; 1.0231x over previous
//
#include <hip/hip_runtime.h>
#include <hip/hip_bf16.h>

// LlamaMLPInfer: SwiGLU MLP with group(128)-dequantized int4 weights.
// R10: R9 (pre-dequant + counted-vmcnt phased K-loops, T3+T4+T5) with the
// post-MFMA barrier removed from every phase (1 barrier per phase).
// Waves skew so reads(p+1) overlap MFMA(p) across waves; pre-MFMA
// SBAR+lgkmcnt(0) still guards data readiness; tile-head vmcnt(4)/(6)+SBAR
// guards buffer turnover.

#define HDIM 4096
#define IDIM 14336
#define MTOK 4096
#define GRP 128

typedef __attribute__((ext_vector_type(8))) short bf16x8;
typedef __attribute__((ext_vector_type(4))) float f32x4;
typedef __attribute__((ext_vector_type(4))) unsigned short u16x4;

#define WAIT_LGKM0 asm volatile("s_waitcnt lgkmcnt(0)" ::: "memory")
#define WAIT_VM(N) asm volatile("s_waitcnt vmcnt(" #N ")" ::: "memory")
#define SBAR       __builtin_amdgcn_s_barrier()
#define SCHB       __builtin_amdgcn_sched_barrier(0)

__device__ __forceinline__ unsigned short f2bf(float f) {
  union { float f; unsigned int u; } v; v.f = f;
  return (unsigned short)((v.u + 0x7fffu + ((v.u >> 16) & 1u)) >> 16);  // RNE
}
__device__ __forceinline__ unsigned pk2(float a, float b) {
  union { float f; unsigned u; } ua, ub; ua.f = a; ub.f = b;
  return __builtin_amdgcn_perm(ub.u, ua.u, 0x07060302u);
}

#define GLD16(G, L)                                                           \
  __builtin_amdgcn_global_load_lds(                                           \
      (const __attribute__((address_space(1))) unsigned int*)(G),             \
      (__attribute__((address_space(3))) unsigned int*)(L), 16, 0, 0)

// ---------------- x fp32 -> bf16 ----------------
__global__ __launch_bounds__(256) void cvt_x_kernel(const float* __restrict__ x,
                                                    unsigned short* __restrict__ xb) {
  const int n = MTOK * HDIM;
  const int stride = gridDim.x * 256 * 4;
  for (int i = (blockIdx.x * 256 + threadIdx.x) * 4; i < n; i += stride) {
    float4 v = *reinterpret_cast<const float4*>(x + i);
    u16x4 o;
    o[0] = f2bf(v.x); o[1] = f2bf(v.y); o[2] = f2bf(v.z); o[3] = f2bf(v.w);
    *reinterpret_cast<u16x4*>(xb + i) = o;
  }
}

// ---------------- weight dequant ----------------
__global__ __launch_bounds__(256) void deq_kernel(const int* __restrict__ q,
                                                  const float* __restrict__ s,
                                                  unsigned short* __restrict__ w,
                                                  int In) {
  const int row  = blockIdx.y;
  const int col0 = blockIdx.x * 2048 + threadIdx.x * 8;
  const long base = (long)row * In + col0;
  const float sc = s[row * (In / GRP) + (col0 >> 7)];
  const int4* p = (const int4*)(q + base);
  int4 a0 = p[0], a1 = p[1];
  uint4 o;
  o.x = pk2((float)a0.x * sc, (float)a0.y * sc);
  o.y = pk2((float)a0.z * sc, (float)a0.w * sc);
  o.z = pk2((float)a1.x * sc, (float)a1.y * sc);
  o.w = pk2((float)a1.z * sc, (float)a1.w * sc);
  *(uint4*)(w + base) = o;
}

// ================= fused gate+up GEMM =================
// 256x128, BK=64, 512 thr (8 waves, 4Mx2N). A 3-buf, B 2-buf. vmcnt(4) head.
__global__ __launch_bounds__(512, 2) void gateup_bf16(
    const unsigned short* __restrict__ xb,
    const unsigned short* __restrict__ wg,
    const unsigned short* __restrict__ wu,
    unsigned short* __restrict__ inter)
{
  __shared__ unsigned short As[3 * 256 * 64];   // 96 KB
  __shared__ unsigned short Bgs[2 * 128 * 64];  // 32 KB
  __shared__ unsigned short Bus[2 * 128 * 64];  // 32 KB

  const int tid = threadIdx.x, lane = tid & 63, wid = tid >> 6;
  const int wm = wid >> 1, wn = wid & 1;
  const int p = blockIdx.x;
  const int l = (p & 7) * 224 + (p >> 3);   // XCD-chunked, 1792 blocks
  const int m0 = (l & 15) * 256, n0 = (l >> 4) * 128;
  const int lr = lane & 15, lc = lane >> 4;

  const int ra   = tid >> 3;
  const int scol = ((tid & 7) ^ (ra & 7)) << 3;
  const unsigned short* pa  = xb + (long)(m0 + ra) * HDIM + scol;
  const unsigned short* pbg = wg + (long)(n0 + ra) * HDIM + scol;
  const unsigned short* pbu = wu + (long)(n0 + ra) * HDIM + scol;

#define A1(KT, BUF, IT)                                                       \
  GLD16(pa + (long)(IT) * 64 * HDIM + (long)(KT) * 64,                        \
        (unsigned short*)As + (BUF) * 16384 + (IT) * 4096 + wid * 512)
#define BG1(KT, BUF, IT)                                                      \
  GLD16(pbg + (long)(IT) * 64 * HDIM + (long)(KT) * 64,                       \
        (unsigned short*)Bgs + (BUF) * 8192 + (IT) * 4096 + wid * 512)
#define BU1(KT, BUF, IT)                                                      \
  GLD16(pbu + (long)(IT) * 64 * HDIM + (long)(KT) * 64,                       \
        (unsigned short*)Bus + (BUF) * 8192 + (IT) * 4096 + wid * 512)

  f32x4 accg[4][4], accu[4][4];
  const f32x4 zero = {0.f, 0.f, 0.f, 0.f};
#pragma unroll
  for (int i = 0; i < 4; ++i)
#pragma unroll
    for (int j = 0; j < 4; ++j) { accg[i][j] = zero; accu[i][j] = zero; }

  // prologue: in-flight order must be [A(0)x4, B(0)x4, A(1)x4]
  A1(0, 0, 0); A1(0, 0, 1); A1(0, 0, 2); A1(0, 0, 3);
  SCHB;
  BG1(0, 0, 0); BG1(0, 0, 1); BU1(0, 0, 0); BU1(0, 0, 1);
  SCHB;
  A1(1, 1, 0); A1(1, 1, 1); A1(1, 1, 2); A1(1, 1, 3);
  SCHB;

  const int NK = HDIM / 64;   // 64
#pragma unroll 1
  for (int kt = 0; kt < NK; ++kt) {
    // head: retire A(kt)+B(kt) (8 oldest of 12); A(kt+1) stays in flight
    WAIT_VM(4);
    SCHB;
    SBAR;
    SCHB;
    const unsigned short* Ab  = (const unsigned short*)As  + (kt % 3) * 16384;
    const unsigned short* Bgb = (const unsigned short*)Bgs + (kt & 1) * 8192;
    const unsigned short* Bub = (const unsigned short*)Bus + (kt & 1) * 8192;
    const int ktb = (kt + 1 < NK) ? kt + 1 : NK - 1;   // B stage src (1-lead)
    const int wrb = (kt + 1) & 1;
    const int kta = (kt + 2 < NK) ? kt + 2 : NK - 1;   // A stage src (2-lead)
    const int wra = (kt + 2) % 3;
    const int soff0 = (lc ^ (lr & 7)) << 3;
    const int soff1 = ((4 + lc) ^ (lr & 7)) << 3;
    bf16x8 af[4], bfr[4];

    // ---- ph0: gate, ks0 ----
#pragma unroll
    for (int mi = 0; mi < 4; ++mi)
      af[mi] = *(const bf16x8*)&Ab[(wm * 64 + mi * 16 + lr) * 64 + soff0];
#pragma unroll
    for (int ni = 0; ni < 4; ++ni)
      bfr[ni] = *(const bf16x8*)&Bgb[(wn * 64 + ni * 16 + lr) * 64 + soff0];
    BG1(ktb, wrb, 0); BG1(ktb, wrb, 1);
    SCHB; SBAR; WAIT_LGKM0; SCHB;
    __builtin_amdgcn_s_setprio(1);
#pragma unroll
    for (int ni = 0; ni < 4; ++ni)
#pragma unroll
      for (int mi = 0; mi < 4; ++mi)
        accg[mi][ni] = __builtin_amdgcn_mfma_f32_16x16x32_bf16(af[mi], bfr[ni], accg[mi][ni], 0, 0, 0);
    __builtin_amdgcn_s_setprio(0);
    // (no post-MFMA barrier: next phase's reads overlap other waves' MFMA)

    // ---- ph1: up, ks0 (af reused) ----
#pragma unroll
    for (int ni = 0; ni < 4; ++ni)
      bfr[ni] = *(const bf16x8*)&Bub[(wn * 64 + ni * 16 + lr) * 64 + soff0];
    BU1(ktb, wrb, 0); BU1(ktb, wrb, 1);
    SCHB; SBAR; WAIT_LGKM0; SCHB;
    __builtin_amdgcn_s_setprio(1);
#pragma unroll
    for (int ni = 0; ni < 4; ++ni)
#pragma unroll
      for (int mi = 0; mi < 4; ++mi)
        accu[mi][ni] = __builtin_amdgcn_mfma_f32_16x16x32_bf16(af[mi], bfr[ni], accu[mi][ni], 0, 0, 0);
    __builtin_amdgcn_s_setprio(0);

    // ---- ph2: gate, ks1 ----
#pragma unroll
    for (int mi = 0; mi < 4; ++mi)
      af[mi] = *(const bf16x8*)&Ab[(wm * 64 + mi * 16 + lr) * 64 + soff1];
#pragma unroll
    for (int ni = 0; ni < 4; ++ni)
      bfr[ni] = *(const bf16x8*)&Bgb[(wn * 64 + ni * 16 + lr) * 64 + soff1];
    A1(kta, wra, 0); A1(kta, wra, 1);
    SCHB; SBAR; WAIT_LGKM0; SCHB;
    __builtin_amdgcn_s_setprio(1);
#pragma unroll
    for (int ni = 0; ni < 4; ++ni)
#pragma unroll
      for (int mi = 0; mi < 4; ++mi)
        accg[mi][ni] = __builtin_amdgcn_mfma_f32_16x16x32_bf16(af[mi], bfr[ni], accg[mi][ni], 0, 0, 0);
    __builtin_amdgcn_s_setprio(0);

    // ---- ph3: up, ks1 ----
#pragma unroll
    for (int ni = 0; ni < 4; ++ni)
      bfr[ni] = *(const bf16x8*)&Bub[(wn * 64 + ni * 16 + lr) * 64 + soff1];
    A1(kta, wra, 2); A1(kta, wra, 3);
    SCHB; SBAR; WAIT_LGKM0; SCHB;
    __builtin_amdgcn_s_setprio(1);
#pragma unroll
    for (int ni = 0; ni < 4; ++ni)
#pragma unroll
      for (int mi = 0; mi < 4; ++mi)
        accu[mi][ni] = __builtin_amdgcn_mfma_f32_16x16x32_bf16(af[mi], bfr[ni], accu[mi][ni], 0, 0, 0);
    __builtin_amdgcn_s_setprio(0);
    SCHB;   // tile-trailing rendezvous = next head SBAR
  }

  // ---- epilogue: silu(g)*u -> bf16 ----
  const int r0 = m0 + wm * 64, c0 = n0 + wn * 64;
#pragma unroll
  for (int mi = 0; mi < 4; ++mi)
#pragma unroll
    for (int ni = 0; ni < 4; ++ni)
#pragma unroll
      for (int r = 0; r < 4; ++r) {
        float g = accg[mi][ni][r], u = accu[mi][ni][r];
        float sv = g / (1.f + __expf(-g));
        int row = r0 + mi * 16 + lc * 4 + r;
        int col = c0 + ni * 16 + lr;
        inter[(long)row * IDIM + col] = f2bf(sv * u);
      }
#undef A1
#undef BG1
#undef BU1
}

// ================= down GEMM =================
// 256x128, BK=64. A+B 3-buf (2-lead). vmcnt(6) head. 2 phases/tile.
__global__ __launch_bounds__(512, 2) void down_bf16(
    const unsigned short* __restrict__ inter,
    const unsigned short* __restrict__ wd,
    float* __restrict__ out)
{
  __shared__ unsigned short As[3 * 256 * 64];  // 96 KB
  __shared__ unsigned short Bs[3 * 128 * 64];  // 48 KB

  const int tid = threadIdx.x, lane = tid & 63, wid = tid >> 6;
  const int wm = wid >> 1, wn = wid & 1;
  const int p = blockIdx.x;
  const int l = (p & 7) * 64 + (p >> 3);    // 512 blocks
  const int m0 = (l & 15) * 256, n0 = (l >> 4) * 128;
  const int lr = lane & 15, lc = lane >> 4;

  const int ra   = tid >> 3;
  const int scol = ((tid & 7) ^ (ra & 7)) << 3;
  const unsigned short* pa = inter + (long)(m0 + ra) * IDIM + scol;
  const unsigned short* pb = wd + (long)(n0 + ra) * IDIM + scol;

#define DA1(KT, BUF, IT)                                                      \
  GLD16(pa + (long)(IT) * 64 * IDIM + (long)(KT) * 64,                        \
        (unsigned short*)As + (BUF) * 16384 + (IT) * 4096 + wid * 512)
#define DB1(KT, BUF, IT)                                                      \
  GLD16(pb + (long)(IT) * 64 * IDIM + (long)(KT) * 64,                        \
        (unsigned short*)Bs + (BUF) * 8192 + (IT) * 4096 + wid * 512)

  f32x4 acc[4][4];
  const f32x4 zero = {0.f, 0.f, 0.f, 0.f};
#pragma unroll
  for (int i = 0; i < 4; ++i)
#pragma unroll
    for (int j = 0; j < 4; ++j) acc[i][j] = zero;

  // prologue: order [B(0)2, A(0)4, B(1)2, A(1)4]
  DB1(0, 0, 0); DB1(0, 0, 1);
  SCHB;
  DA1(0, 0, 0); DA1(0, 0, 1); DA1(0, 0, 2); DA1(0, 0, 3);
  SCHB;
  DB1(1, 1, 0); DB1(1, 1, 1);
  SCHB;
  DA1(1, 1, 0); DA1(1, 1, 1); DA1(1, 1, 2); DA1(1, 1, 3);
  SCHB;

  const int NK = IDIM / 64;   // 224
#pragma unroll 1
  for (int kt = 0; kt < NK; ++kt) {
    WAIT_VM(6);     // retire tile kt's 6; kt+1's stay in flight
    SCHB;
    SBAR;
    SCHB;
    const unsigned short* Ab = (const unsigned short*)As + (kt % 3) * 16384;
    const unsigned short* Bb = (const unsigned short*)Bs + (kt % 3) * 8192;
    const int ktc = (kt + 2 < NK) ? kt + 2 : NK - 1;
    const int wrc = (kt + 2) % 3;
    const int soff0 = (lc ^ (lr & 7)) << 3;
    const int soff1 = ((4 + lc) ^ (lr & 7)) << 3;
    bf16x8 af[4], bfr[4];

    // ---- ph0: ks0 ----
#pragma unroll
    for (int mi = 0; mi < 4; ++mi)
      af[mi] = *(const bf16x8*)&Ab[(wm * 64 + mi * 16 + lr) * 64 + soff0];
#pragma unroll
    for (int ni = 0; ni < 4; ++ni)
      bfr[ni] = *(const bf16x8*)&Bb[(wn * 64 + ni * 16 + lr) * 64 + soff0];
    DB1(ktc, wrc, 0); DB1(ktc, wrc, 1); DA1(ktc, wrc, 0);
    SCHB; SBAR; WAIT_LGKM0; SCHB;
    __builtin_amdgcn_s_setprio(1);
#pragma unroll
    for (int ni = 0; ni < 4; ++ni)
#pragma unroll
      for (int mi = 0; mi < 4; ++mi)
        acc[mi][ni] = __builtin_amdgcn_mfma_f32_16x16x32_bf16(af[mi], bfr[ni], acc[mi][ni], 0, 0, 0);
    __builtin_amdgcn_s_setprio(0);
    // (no post-MFMA barrier)

    // ---- ph1: ks1 ----
#pragma unroll
    for (int mi = 0; mi < 4; ++mi)
      af[mi] = *(const bf16x8*)&Ab[(wm * 64 + mi * 16 + lr) * 64 + soff1];
#pragma unroll
    for (int ni = 0; ni < 4; ++ni)
      bfr[ni] = *(const bf16x8*)&Bb[(wn * 64 + ni * 16 + lr) * 64 + soff1];
    DA1(ktc, wrc, 1); DA1(ktc, wrc, 2); DA1(ktc, wrc, 3);
    SCHB; SBAR; WAIT_LGKM0; SCHB;
    __builtin_amdgcn_s_setprio(1);
#pragma unroll
    for (int ni = 0; ni < 4; ++ni)
#pragma unroll
      for (int mi = 0; mi < 4; ++mi)
        acc[mi][ni] = __builtin_amdgcn_mfma_f32_16x16x32_bf16(af[mi], bfr[ni], acc[mi][ni], 0, 0, 0);
    __builtin_amdgcn_s_setprio(0);
    SCHB;   // next head SBAR closes the tile
  }

  const int r0 = m0 + wm * 64, c0 = n0 + wn * 64;
#pragma unroll
  for (int mi = 0; mi < 4; ++mi)
#pragma unroll
    for (int ni = 0; ni < 4; ++ni)
#pragma unroll
      for (int r = 0; r < 4; ++r) {
        int row = r0 + mi * 16 + lc * 4 + r;
        int col = c0 + ni * 16 + lr;
        out[(long)row * HDIM + col] = acc[mi][ni][r];
      }
#undef DA1
#undef DB1
}

extern "C" void kernel_launch(void* const* d_in, const int* in_sizes, int n_in,
                              void* d_out, int out_size, void* d_ws, size_t ws_size,
                              hipStream_t stream) {
  const float* x   = (const float*)d_in[0];
  const int*   gq  = (const int*)d_in[1];
  const float* gsc = (const float*)d_in[2];
  const int*   uq  = (const int*)d_in[3];
  const float* usc = (const float*)d_in[4];
  const int*   dq  = (const int*)d_in[5];
  const float* dsc = (const float*)d_in[6];
  float* out = (float*)d_out;

  unsigned short* xb    = (unsigned short*)d_ws;                    // 32 MiB
  unsigned short* inter = xb + (size_t)MTOK * HDIM;                 // 112 MiB
  unsigned short* wgb   = inter + (size_t)MTOK * IDIM;              // 112 MiB
  unsigned short* wub   = wgb + (size_t)IDIM * HDIM;                // 112 MiB

  hipLaunchKernelGGL(cvt_x_kernel, dim3(2048), dim3(256), 0, stream, x, xb);
  hipLaunchKernelGGL(deq_kernel, dim3(HDIM / 2048, IDIM), dim3(256), 0, stream,
                     gq, gsc, wgb, HDIM);
  hipLaunchKernelGGL(deq_kernel, dim3(HDIM / 2048, IDIM), dim3(256), 0, stream,
                     uq, usc, wub, HDIM);
  hipLaunchKernelGGL(gateup_bf16, dim3(1792), dim3(512), 0, stream,
                     xb, wgb, wub, inter);
  // down weights reuse the (now free) gate-weight region
  hipLaunchKernelGGL(deq_kernel, dim3(IDIM / 2048, HDIM), dim3(256), 0, stream,
                     dq, dsc, wgb, IDIM);
  hipLaunchKernelGGL(down_bf16, dim3(512), dim3(512), 0, stream,
                     inter, wgb, out);
}

// Round 11
// 1412.031 us; speedup vs baseline: 7.0103x; 1.0998x over previous
//
#include <hip/hip_runtime.h>
#include <hip/hip_bf16.h>

// LlamaMLPInfer: SwiGLU MLP with group(128)-dequantized int4 weights.
// R11: R10 + down GEMM retiled to 256x256 (per-wave 128x64, m201 shape):
// 25% lower LDS-read/FLOP, half the staging writes per output. 2-buf A+B
// (128KB), 1-lead prefetch issued early in tile (stage-B in ph0, stage-A in
// ph1), tail vmcnt(0) retires ~free (loads >=1300cy old). Gateup unchanged.

#define HDIM 4096
#define IDIM 14336
#define MTOK 4096
#define GRP 128

typedef __attribute__((ext_vector_type(8))) short bf16x8;
typedef __attribute__((ext_vector_type(4))) float f32x4;
typedef __attribute__((ext_vector_type(4))) unsigned short u16x4;

#define WAIT_LGKM0 asm volatile("s_waitcnt lgkmcnt(0)" ::: "memory")
#define WAIT_VM(N) asm volatile("s_waitcnt vmcnt(" #N ")" ::: "memory")
#define SBAR       __builtin_amdgcn_s_barrier()
#define SCHB       __builtin_amdgcn_sched_barrier(0)

__device__ __forceinline__ unsigned short f2bf(float f) {
  union { float f; unsigned int u; } v; v.f = f;
  return (unsigned short)((v.u + 0x7fffu + ((v.u >> 16) & 1u)) >> 16);  // RNE
}
__device__ __forceinline__ unsigned pk2(float a, float b) {
  union { float f; unsigned u; } ua, ub; ua.f = a; ub.f = b;
  return __builtin_amdgcn_perm(ub.u, ua.u, 0x07060302u);
}

#define GLD16(G, L)                                                           \
  __builtin_amdgcn_global_load_lds(                                           \
      (const __attribute__((address_space(1))) unsigned int*)(G),             \
      (__attribute__((address_space(3))) unsigned int*)(L), 16, 0, 0)

// ---------------- x fp32 -> bf16 ----------------
__global__ __launch_bounds__(256) void cvt_x_kernel(const float* __restrict__ x,
                                                    unsigned short* __restrict__ xb) {
  const int n = MTOK * HDIM;
  const int stride = gridDim.x * 256 * 4;
  for (int i = (blockIdx.x * 256 + threadIdx.x) * 4; i < n; i += stride) {
    float4 v = *reinterpret_cast<const float4*>(x + i);
    u16x4 o;
    o[0] = f2bf(v.x); o[1] = f2bf(v.y); o[2] = f2bf(v.z); o[3] = f2bf(v.w);
    *reinterpret_cast<u16x4*>(xb + i) = o;
  }
}

// ---------------- weight dequant ----------------
__global__ __launch_bounds__(256) void deq_kernel(const int* __restrict__ q,
                                                  const float* __restrict__ s,
                                                  unsigned short* __restrict__ w,
                                                  int In) {
  const int row  = blockIdx.y;
  const int col0 = blockIdx.x * 2048 + threadIdx.x * 8;
  const long base = (long)row * In + col0;
  const float sc = s[row * (In / GRP) + (col0 >> 7)];
  const int4* p = (const int4*)(q + base);
  int4 a0 = p[0], a1 = p[1];
  uint4 o;
  o.x = pk2((float)a0.x * sc, (float)a0.y * sc);
  o.y = pk2((float)a0.z * sc, (float)a0.w * sc);
  o.z = pk2((float)a1.x * sc, (float)a1.y * sc);
  o.w = pk2((float)a1.z * sc, (float)a1.w * sc);
  *(uint4*)(w + base) = o;
}

// ================= fused gate+up GEMM (unchanged from R10) =================
__global__ __launch_bounds__(512, 2) void gateup_bf16(
    const unsigned short* __restrict__ xb,
    const unsigned short* __restrict__ wg,
    const unsigned short* __restrict__ wu,
    unsigned short* __restrict__ inter)
{
  __shared__ unsigned short As[3 * 256 * 64];   // 96 KB
  __shared__ unsigned short Bgs[2 * 128 * 64];  // 32 KB
  __shared__ unsigned short Bus[2 * 128 * 64];  // 32 KB

  const int tid = threadIdx.x, lane = tid & 63, wid = tid >> 6;
  const int wm = wid >> 1, wn = wid & 1;
  const int p = blockIdx.x;
  const int l = (p & 7) * 224 + (p >> 3);   // XCD-chunked, 1792 blocks
  const int m0 = (l & 15) * 256, n0 = (l >> 4) * 128;
  const int lr = lane & 15, lc = lane >> 4;

  const int ra   = tid >> 3;
  const int scol = ((tid & 7) ^ (ra & 7)) << 3;
  const unsigned short* pa  = xb + (long)(m0 + ra) * HDIM + scol;
  const unsigned short* pbg = wg + (long)(n0 + ra) * HDIM + scol;
  const unsigned short* pbu = wu + (long)(n0 + ra) * HDIM + scol;

#define A1(KT, BUF, IT)                                                       \
  GLD16(pa + (long)(IT) * 64 * HDIM + (long)(KT) * 64,                        \
        (unsigned short*)As + (BUF) * 16384 + (IT) * 4096 + wid * 512)
#define BG1(KT, BUF, IT)                                                      \
  GLD16(pbg + (long)(IT) * 64 * HDIM + (long)(KT) * 64,                       \
        (unsigned short*)Bgs + (BUF) * 8192 + (IT) * 4096 + wid * 512)
#define BU1(KT, BUF, IT)                                                      \
  GLD16(pbu + (long)(IT) * 64 * HDIM + (long)(KT) * 64,                       \
        (unsigned short*)Bus + (BUF) * 8192 + (IT) * 4096 + wid * 512)

  f32x4 accg[4][4], accu[4][4];
  const f32x4 zero = {0.f, 0.f, 0.f, 0.f};
#pragma unroll
  for (int i = 0; i < 4; ++i)
#pragma unroll
    for (int j = 0; j < 4; ++j) { accg[i][j] = zero; accu[i][j] = zero; }

  // prologue: in-flight order must be [A(0)x4, B(0)x4, A(1)x4]
  A1(0, 0, 0); A1(0, 0, 1); A1(0, 0, 2); A1(0, 0, 3);
  SCHB;
  BG1(0, 0, 0); BG1(0, 0, 1); BU1(0, 0, 0); BU1(0, 0, 1);
  SCHB;
  A1(1, 1, 0); A1(1, 1, 1); A1(1, 1, 2); A1(1, 1, 3);
  SCHB;

  const int NK = HDIM / 64;   // 64
#pragma unroll 1
  for (int kt = 0; kt < NK; ++kt) {
    WAIT_VM(4);
    SCHB;
    SBAR;
    SCHB;
    const unsigned short* Ab  = (const unsigned short*)As  + (kt % 3) * 16384;
    const unsigned short* Bgb = (const unsigned short*)Bgs + (kt & 1) * 8192;
    const unsigned short* Bub = (const unsigned short*)Bus + (kt & 1) * 8192;
    const int ktb = (kt + 1 < NK) ? kt + 1 : NK - 1;
    const int wrb = (kt + 1) & 1;
    const int kta = (kt + 2 < NK) ? kt + 2 : NK - 1;
    const int wra = (kt + 2) % 3;
    const int soff0 = (lc ^ (lr & 7)) << 3;
    const int soff1 = ((4 + lc) ^ (lr & 7)) << 3;
    bf16x8 af[4], bfr[4];

    // ---- ph0: gate, ks0 ----
#pragma unroll
    for (int mi = 0; mi < 4; ++mi)
      af[mi] = *(const bf16x8*)&Ab[(wm * 64 + mi * 16 + lr) * 64 + soff0];
#pragma unroll
    for (int ni = 0; ni < 4; ++ni)
      bfr[ni] = *(const bf16x8*)&Bgb[(wn * 64 + ni * 16 + lr) * 64 + soff0];
    BG1(ktb, wrb, 0); BG1(ktb, wrb, 1);
    SCHB; SBAR; WAIT_LGKM0; SCHB;
    __builtin_amdgcn_s_setprio(1);
#pragma unroll
    for (int ni = 0; ni < 4; ++ni)
#pragma unroll
      for (int mi = 0; mi < 4; ++mi)
        accg[mi][ni] = __builtin_amdgcn_mfma_f32_16x16x32_bf16(af[mi], bfr[ni], accg[mi][ni], 0, 0, 0);
    __builtin_amdgcn_s_setprio(0);

    // ---- ph1: up, ks0 (af reused) ----
#pragma unroll
    for (int ni = 0; ni < 4; ++ni)
      bfr[ni] = *(const bf16x8*)&Bub[(wn * 64 + ni * 16 + lr) * 64 + soff0];
    BU1(ktb, wrb, 0); BU1(ktb, wrb, 1);
    SCHB; SBAR; WAIT_LGKM0; SCHB;
    __builtin_amdgcn_s_setprio(1);
#pragma unroll
    for (int ni = 0; ni < 4; ++ni)
#pragma unroll
      for (int mi = 0; mi < 4; ++mi)
        accu[mi][ni] = __builtin_amdgcn_mfma_f32_16x16x32_bf16(af[mi], bfr[ni], accu[mi][ni], 0, 0, 0);
    __builtin_amdgcn_s_setprio(0);

    // ---- ph2: gate, ks1 ----
#pragma unroll
    for (int mi = 0; mi < 4; ++mi)
      af[mi] = *(const bf16x8*)&Ab[(wm * 64 + mi * 16 + lr) * 64 + soff1];
#pragma unroll
    for (int ni = 0; ni < 4; ++ni)
      bfr[ni] = *(const bf16x8*)&Bgb[(wn * 64 + ni * 16 + lr) * 64 + soff1];
    A1(kta, wra, 0); A1(kta, wra, 1);
    SCHB; SBAR; WAIT_LGKM0; SCHB;
    __builtin_amdgcn_s_setprio(1);
#pragma unroll
    for (int ni = 0; ni < 4; ++ni)
#pragma unroll
      for (int mi = 0; mi < 4; ++mi)
        accg[mi][ni] = __builtin_amdgcn_mfma_f32_16x16x32_bf16(af[mi], bfr[ni], accg[mi][ni], 0, 0, 0);
    __builtin_amdgcn_s_setprio(0);

    // ---- ph3: up, ks1 ----
#pragma unroll
    for (int ni = 0; ni < 4; ++ni)
      bfr[ni] = *(const bf16x8*)&Bub[(wn * 64 + ni * 16 + lr) * 64 + soff1];
    A1(kta, wra, 2); A1(kta, wra, 3);
    SCHB; SBAR; WAIT_LGKM0; SCHB;
    __builtin_amdgcn_s_setprio(1);
#pragma unroll
    for (int ni = 0; ni < 4; ++ni)
#pragma unroll
      for (int mi = 0; mi < 4; ++mi)
        accu[mi][ni] = __builtin_amdgcn_mfma_f32_16x16x32_bf16(af[mi], bfr[ni], accu[mi][ni], 0, 0, 0);
    __builtin_amdgcn_s_setprio(0);
    SCHB;
  }

  const int r0 = m0 + wm * 64, c0 = n0 + wn * 64;
#pragma unroll
  for (int mi = 0; mi < 4; ++mi)
#pragma unroll
    for (int ni = 0; ni < 4; ++ni)
#pragma unroll
      for (int r = 0; r < 4; ++r) {
        float g = accg[mi][ni][r], u = accu[mi][ni][r];
        float sv = g / (1.f + __expf(-g));
        int row = r0 + mi * 16 + lc * 4 + r;
        int col = c0 + ni * 16 + lr;
        inter[(long)row * IDIM + col] = f2bf(sv * u);
      }
#undef A1
#undef BG1
#undef BU1
}

// ================= down GEMM: 256x256 tile =================
// 8 waves 2Mx4N, per-wave 128x64. A+B 2-buf (128KB). 2 phases/tile.
// stage(kt+1): B in ph0, A in ph1; tail vmcnt(0) (loads >=1 phase old).
__global__ __launch_bounds__(512, 2) void down_bf16(
    const unsigned short* __restrict__ inter,
    const unsigned short* __restrict__ wd,
    float* __restrict__ out)
{
  __shared__ unsigned short As[2 * 256 * 64];  // 64 KB
  __shared__ unsigned short Bs[2 * 256 * 64];  // 64 KB

  const int tid = threadIdx.x, lane = tid & 63, wid = tid >> 6;
  const int wm = wid >> 2, wn = wid & 3;          // 2M x 4N
  const int p = blockIdx.x;                       // 256 blocks
  const int l = (p & 7) * 32 + (p >> 3);          // XCD-chunked
  const int m0 = (l & 15) * 256, n0 = (l >> 4) * 256;
  const int lr = lane & 15, lc = lane >> 4;

  const int ra   = tid >> 3;
  const int scol = ((tid & 7) ^ (ra & 7)) << 3;
  const unsigned short* pa = inter + (long)(m0 + ra) * IDIM + scol;
  const unsigned short* pb = wd + (long)(n0 + ra) * IDIM + scol;

#define DA1(KT, BUF, IT)                                                      \
  GLD16(pa + (long)(IT) * 64 * IDIM + (long)(KT) * 64,                        \
        (unsigned short*)As + (BUF) * 16384 + (IT) * 4096 + wid * 512)
#define DB1(KT, BUF, IT)                                                      \
  GLD16(pb + (long)(IT) * 64 * IDIM + (long)(KT) * 64,                        \
        (unsigned short*)Bs + (BUF) * 16384 + (IT) * 4096 + wid * 512)

  f32x4 acc[8][4];
  const f32x4 zero = {0.f, 0.f, 0.f, 0.f};
#pragma unroll
  for (int i = 0; i < 8; ++i)
#pragma unroll
    for (int j = 0; j < 4; ++j) acc[i][j] = zero;

  // prologue: stage tile 0 -> parity 0
  DB1(0, 0, 0); DB1(0, 0, 1); DB1(0, 0, 2); DB1(0, 0, 3);
  DA1(0, 0, 0); DA1(0, 0, 1); DA1(0, 0, 2); DA1(0, 0, 3);
  SCHB;
  WAIT_VM(0);
  SBAR;
  SCHB;

  const int NK = IDIM / 64;   // 224
#pragma unroll 1
  for (int kt = 0; kt < NK; ++kt) {
    const int RD = kt & 1, WR = RD ^ 1;
    const int ktn = (kt + 1 < NK) ? kt + 1 : NK - 1;
    const unsigned short* Ab = (const unsigned short*)As + RD * 16384;
    const unsigned short* Bb = (const unsigned short*)Bs + RD * 16384;
    const int soff0 = (lc ^ (lr & 7)) << 3;
    const int soff1 = ((4 + lc) ^ (lr & 7)) << 3;
    bf16x8 af[8], bfr[4];

    // ---- ph0: ks0 ----
#pragma unroll
    for (int mi = 0; mi < 8; ++mi)
      af[mi] = *(const bf16x8*)&Ab[(wm * 128 + mi * 16 + lr) * 64 + soff0];
#pragma unroll
    for (int ni = 0; ni < 4; ++ni)
      bfr[ni] = *(const bf16x8*)&Bb[(wn * 64 + ni * 16 + lr) * 64 + soff0];
    DB1(ktn, WR, 0); DB1(ktn, WR, 1); DB1(ktn, WR, 2); DB1(ktn, WR, 3);
    SCHB; WAIT_LGKM0; SCHB;
    __builtin_amdgcn_s_setprio(1);
#pragma unroll
    for (int ni = 0; ni < 4; ++ni)
#pragma unroll
      for (int mi = 0; mi < 8; ++mi)
        acc[mi][ni] = __builtin_amdgcn_mfma_f32_16x16x32_bf16(af[mi], bfr[ni], acc[mi][ni], 0, 0, 0);
    __builtin_amdgcn_s_setprio(0);

    // ---- ph1: ks1 ----
#pragma unroll
    for (int mi = 0; mi < 8; ++mi)
      af[mi] = *(const bf16x8*)&Ab[(wm * 128 + mi * 16 + lr) * 64 + soff1];
#pragma unroll
    for (int ni = 0; ni < 4; ++ni)
      bfr[ni] = *(const bf16x8*)&Bb[(wn * 64 + ni * 16 + lr) * 64 + soff1];
    DA1(ktn, WR, 0); DA1(ktn, WR, 1); DA1(ktn, WR, 2); DA1(ktn, WR, 3);
    SCHB; WAIT_LGKM0; SCHB;
    __builtin_amdgcn_s_setprio(1);
#pragma unroll
    for (int ni = 0; ni < 4; ++ni)
#pragma unroll
      for (int mi = 0; mi < 8; ++mi)
        acc[mi][ni] = __builtin_amdgcn_mfma_f32_16x16x32_bf16(af[mi], bfr[ni], acc[mi][ni], 0, 0, 0);
    __builtin_amdgcn_s_setprio(0);

    // ---- tail: retire next-tile stage (issued >=1 phase ago), rendezvous ----
    SCHB;
    WAIT_VM(0);
    SBAR;
    SCHB;
  }

  const int r0 = m0 + wm * 128, c0 = n0 + wn * 64;
#pragma unroll
  for (int mi = 0; mi < 8; ++mi)
#pragma unroll
    for (int ni = 0; ni < 4; ++ni)
#pragma unroll
      for (int r = 0; r < 4; ++r) {
        int row = r0 + mi * 16 + lc * 4 + r;
        int col = c0 + ni * 16 + lr;
        out[(long)row * HDIM + col] = acc[mi][ni][r];
      }
#undef DA1
#undef DB1
}

extern "C" void kernel_launch(void* const* d_in, const int* in_sizes, int n_in,
                              void* d_out, int out_size, void* d_ws, size_t ws_size,
                              hipStream_t stream) {
  const float* x   = (const float*)d_in[0];
  const int*   gq  = (const int*)d_in[1];
  const float* gsc = (const float*)d_in[2];
  const int*   uq  = (const int*)d_in[3];
  const float* usc = (const float*)d_in[4];
  const int*   dq  = (const int*)d_in[5];
  const float* dsc = (const float*)d_in[6];
  float* out = (float*)d_out;

  unsigned short* xb    = (unsigned short*)d_ws;                    // 32 MiB
  unsigned short* inter = xb + (size_t)MTOK * HDIM;                 // 112 MiB
  unsigned short* wgb   = inter + (size_t)MTOK * IDIM;              // 112 MiB
  unsigned short* wub   = wgb + (size_t)IDIM * HDIM;                // 112 MiB

  hipLaunchKernelGGL(cvt_x_kernel, dim3(2048), dim3(256), 0, stream, x, xb);
  hipLaunchKernelGGL(deq_kernel, dim3(HDIM / 2048, IDIM), dim3(256), 0, stream,
                     gq, gsc, wgb, HDIM);
  hipLaunchKernelGGL(deq_kernel, dim3(HDIM / 2048, IDIM), dim3(256), 0, stream,
                     uq, usc, wub, HDIM);
  hipLaunchKernelGGL(gateup_bf16, dim3(1792), dim3(512), 0, stream,
                     xb, wgb, wub, inter);
  // down weights reuse the (now free) gate-weight region
  hipLaunchKernelGGL(deq_kernel, dim3(IDIM / 2048, HDIM), dim3(256), 0, stream,
                     dq, dsc, wgb, IDIM);
  hipLaunchKernelGGL(down_bf16, dim3(256), dim3(512), 0, stream,
                     inter, wgb, out);
}

// Round 12
// 1387.371 us; speedup vs baseline: 7.1349x; 1.0178x over previous
//
#include <hip/hip_runtime.h>
#include <hip/hip_bf16.h>

// LlamaMLPInfer: SwiGLU MLP with group(128)-dequantized int4 weights.
// R12: gateup ported to the down-style minimal-sync schedule proven in R11:
// 2 phases/tile, per-wave lgkmcnt(0) before MFMA (no per-phase barriers),
// ONE tail vmcnt(0)+SBAR per K-tile. A 2-buf; LDS 128KB. Down unchanged.

#define HDIM 4096
#define IDIM 14336
#define MTOK 4096
#define GRP 128

typedef __attribute__((ext_vector_type(8))) short bf16x8;
typedef __attribute__((ext_vector_type(4))) float f32x4;
typedef __attribute__((ext_vector_type(4))) unsigned short u16x4;

#define WAIT_LGKM0 asm volatile("s_waitcnt lgkmcnt(0)" ::: "memory")
#define WAIT_VM(N) asm volatile("s_waitcnt vmcnt(" #N ")" ::: "memory")
#define SBAR       __builtin_amdgcn_s_barrier()
#define SCHB       __builtin_amdgcn_sched_barrier(0)

__device__ __forceinline__ unsigned short f2bf(float f) {
  union { float f; unsigned int u; } v; v.f = f;
  return (unsigned short)((v.u + 0x7fffu + ((v.u >> 16) & 1u)) >> 16);  // RNE
}
__device__ __forceinline__ unsigned pk2(float a, float b) {
  union { float f; unsigned u; } ua, ub; ua.f = a; ub.f = b;
  return __builtin_amdgcn_perm(ub.u, ua.u, 0x07060302u);
}

#define GLD16(G, L)                                                           \
  __builtin_amdgcn_global_load_lds(                                           \
      (const __attribute__((address_space(1))) unsigned int*)(G),             \
      (__attribute__((address_space(3))) unsigned int*)(L), 16, 0, 0)

// ---------------- x fp32 -> bf16 ----------------
__global__ __launch_bounds__(256) void cvt_x_kernel(const float* __restrict__ x,
                                                    unsigned short* __restrict__ xb) {
  const int n = MTOK * HDIM;
  const int stride = gridDim.x * 256 * 4;
  for (int i = (blockIdx.x * 256 + threadIdx.x) * 4; i < n; i += stride) {
    float4 v = *reinterpret_cast<const float4*>(x + i);
    u16x4 o;
    o[0] = f2bf(v.x); o[1] = f2bf(v.y); o[2] = f2bf(v.z); o[3] = f2bf(v.w);
    *reinterpret_cast<u16x4*>(xb + i) = o;
  }
}

// ---------------- weight dequant ----------------
__global__ __launch_bounds__(256) void deq_kernel(const int* __restrict__ q,
                                                  const float* __restrict__ s,
                                                  unsigned short* __restrict__ w,
                                                  int In) {
  const int row  = blockIdx.y;
  const int col0 = blockIdx.x * 2048 + threadIdx.x * 8;
  const long base = (long)row * In + col0;
  const float sc = s[row * (In / GRP) + (col0 >> 7)];
  const int4* p = (const int4*)(q + base);
  int4 a0 = p[0], a1 = p[1];
  uint4 o;
  o.x = pk2((float)a0.x * sc, (float)a0.y * sc);
  o.y = pk2((float)a0.z * sc, (float)a0.w * sc);
  o.z = pk2((float)a1.x * sc, (float)a1.y * sc);
  o.w = pk2((float)a1.z * sc, (float)a1.w * sc);
  *(uint4*)(w + base) = o;
}

// ================= fused gate+up GEMM =================
// 256x128, BK=64, 512 thr (8 waves, 4Mx2N). A/Bg/Bu 2-buf (128KB).
// 2 phases/tile, 1 barrier/tile (down-style minimal sync).
__global__ __launch_bounds__(512, 2) void gateup_bf16(
    const unsigned short* __restrict__ xb,
    const unsigned short* __restrict__ wg,
    const unsigned short* __restrict__ wu,
    unsigned short* __restrict__ inter)
{
  __shared__ unsigned short As[2 * 256 * 64];   // 64 KB
  __shared__ unsigned short Bgs[2 * 128 * 64];  // 32 KB
  __shared__ unsigned short Bus[2 * 128 * 64];  // 32 KB

  const int tid = threadIdx.x, lane = tid & 63, wid = tid >> 6;
  const int wm = wid >> 1, wn = wid & 1;
  const int p = blockIdx.x;
  const int l = (p & 7) * 224 + (p >> 3);   // XCD-chunked, 1792 blocks
  const int m0 = (l & 15) * 256, n0 = (l >> 4) * 128;
  const int lr = lane & 15, lc = lane >> 4;

  const int ra   = tid >> 3;
  const int scol = ((tid & 7) ^ (ra & 7)) << 3;
  const unsigned short* pa  = xb + (long)(m0 + ra) * HDIM + scol;
  const unsigned short* pbg = wg + (long)(n0 + ra) * HDIM + scol;
  const unsigned short* pbu = wu + (long)(n0 + ra) * HDIM + scol;

#define A1(KT, BUF, IT)                                                       \
  GLD16(pa + (long)(IT) * 64 * HDIM + (long)(KT) * 64,                        \
        (unsigned short*)As + (BUF) * 16384 + (IT) * 4096 + wid * 512)
#define BG1(KT, BUF, IT)                                                      \
  GLD16(pbg + (long)(IT) * 64 * HDIM + (long)(KT) * 64,                       \
        (unsigned short*)Bgs + (BUF) * 8192 + (IT) * 4096 + wid * 512)
#define BU1(KT, BUF, IT)                                                      \
  GLD16(pbu + (long)(IT) * 64 * HDIM + (long)(KT) * 64,                       \
        (unsigned short*)Bus + (BUF) * 8192 + (IT) * 4096 + wid * 512)

  f32x4 accg[4][4], accu[4][4];
  const f32x4 zero = {0.f, 0.f, 0.f, 0.f};
#pragma unroll
  for (int i = 0; i < 4; ++i)
#pragma unroll
    for (int j = 0; j < 4; ++j) { accg[i][j] = zero; accu[i][j] = zero; }

  // prologue: stage tile 0 -> parity 0
  BG1(0, 0, 0); BG1(0, 0, 1); BU1(0, 0, 0); BU1(0, 0, 1);
  A1(0, 0, 0); A1(0, 0, 1); A1(0, 0, 2); A1(0, 0, 3);
  SCHB;
  WAIT_VM(0);
  SBAR;
  SCHB;

  const int NK = HDIM / 64;   // 64
#pragma unroll 1
  for (int kt = 0; kt < NK; ++kt) {
    const int RD = kt & 1, WR = RD ^ 1;
    const int ktn = (kt + 1 < NK) ? kt + 1 : NK - 1;
    const unsigned short* Ab  = (const unsigned short*)As  + RD * 16384;
    const unsigned short* Bgb = (const unsigned short*)Bgs + RD * 8192;
    const unsigned short* Bub = (const unsigned short*)Bus + RD * 8192;
    const int soff0 = (lc ^ (lr & 7)) << 3;
    const int soff1 = ((4 + lc) ^ (lr & 7)) << 3;
    bf16x8 af[4], bg[4], bu[4];

    // ---- ph0: ks0 (stage B(t+1)) ----
#pragma unroll
    for (int mi = 0; mi < 4; ++mi)
      af[mi] = *(const bf16x8*)&Ab[(wm * 64 + mi * 16 + lr) * 64 + soff0];
#pragma unroll
    for (int ni = 0; ni < 4; ++ni) {
      bg[ni] = *(const bf16x8*)&Bgb[(wn * 64 + ni * 16 + lr) * 64 + soff0];
      bu[ni] = *(const bf16x8*)&Bub[(wn * 64 + ni * 16 + lr) * 64 + soff0];
    }
    BG1(ktn, WR, 0); BG1(ktn, WR, 1); BU1(ktn, WR, 0); BU1(ktn, WR, 1);
    SCHB; WAIT_LGKM0; SCHB;
    __builtin_amdgcn_s_setprio(1);
#pragma unroll
    for (int ni = 0; ni < 4; ++ni)
#pragma unroll
      for (int mi = 0; mi < 4; ++mi) {
        accg[mi][ni] = __builtin_amdgcn_mfma_f32_16x16x32_bf16(af[mi], bg[ni], accg[mi][ni], 0, 0, 0);
        accu[mi][ni] = __builtin_amdgcn_mfma_f32_16x16x32_bf16(af[mi], bu[ni], accu[mi][ni], 0, 0, 0);
      }
    __builtin_amdgcn_s_setprio(0);

    // ---- ph1: ks1 (stage A(t+1)) ----
#pragma unroll
    for (int mi = 0; mi < 4; ++mi)
      af[mi] = *(const bf16x8*)&Ab[(wm * 64 + mi * 16 + lr) * 64 + soff1];
#pragma unroll
    for (int ni = 0; ni < 4; ++ni) {
      bg[ni] = *(const bf16x8*)&Bgb[(wn * 64 + ni * 16 + lr) * 64 + soff1];
      bu[ni] = *(const bf16x8*)&Bub[(wn * 64 + ni * 16 + lr) * 64 + soff1];
    }
    A1(ktn, WR, 0); A1(ktn, WR, 1); A1(ktn, WR, 2); A1(ktn, WR, 3);
    SCHB; WAIT_LGKM0; SCHB;
    __builtin_amdgcn_s_setprio(1);
#pragma unroll
    for (int ni = 0; ni < 4; ++ni)
#pragma unroll
      for (int mi = 0; mi < 4; ++mi) {
        accg[mi][ni] = __builtin_amdgcn_mfma_f32_16x16x32_bf16(af[mi], bg[ni], accg[mi][ni], 0, 0, 0);
        accu[mi][ni] = __builtin_amdgcn_mfma_f32_16x16x32_bf16(af[mi], bu[ni], accu[mi][ni], 0, 0, 0);
      }
    __builtin_amdgcn_s_setprio(0);

    // ---- tail: retire next-tile stage, rendezvous ----
    SCHB;
    WAIT_VM(0);
    SBAR;
    SCHB;
  }

  const int r0 = m0 + wm * 64, c0 = n0 + wn * 64;
#pragma unroll
  for (int mi = 0; mi < 4; ++mi)
#pragma unroll
    for (int ni = 0; ni < 4; ++ni)
#pragma unroll
      for (int r = 0; r < 4; ++r) {
        float g = accg[mi][ni][r], u = accu[mi][ni][r];
        float sv = g / (1.f + __expf(-g));
        int row = r0 + mi * 16 + lc * 4 + r;
        int col = c0 + ni * 16 + lr;
        inter[(long)row * IDIM + col] = f2bf(sv * u);
      }
#undef A1
#undef BG1
#undef BU1
}

// ================= down GEMM: 256x256 tile (unchanged from R11) =================
__global__ __launch_bounds__(512, 2) void down_bf16(
    const unsigned short* __restrict__ inter,
    const unsigned short* __restrict__ wd,
    float* __restrict__ out)
{
  __shared__ unsigned short As[2 * 256 * 64];  // 64 KB
  __shared__ unsigned short Bs[2 * 256 * 64];  // 64 KB

  const int tid = threadIdx.x, lane = tid & 63, wid = tid >> 6;
  const int wm = wid >> 2, wn = wid & 3;          // 2M x 4N
  const int p = blockIdx.x;                       // 256 blocks
  const int l = (p & 7) * 32 + (p >> 3);          // XCD-chunked
  const int m0 = (l & 15) * 256, n0 = (l >> 4) * 256;
  const int lr = lane & 15, lc = lane >> 4;

  const int ra   = tid >> 3;
  const int scol = ((tid & 7) ^ (ra & 7)) << 3;
  const unsigned short* pa = inter + (long)(m0 + ra) * IDIM + scol;
  const unsigned short* pb = wd + (long)(n0 + ra) * IDIM + scol;

#define DA1(KT, BUF, IT)                                                      \
  GLD16(pa + (long)(IT) * 64 * IDIM + (long)(KT) * 64,                        \
        (unsigned short*)As + (BUF) * 16384 + (IT) * 4096 + wid * 512)
#define DB1(KT, BUF, IT)                                                      \
  GLD16(pb + (long)(IT) * 64 * IDIM + (long)(KT) * 64,                        \
        (unsigned short*)Bs + (BUF) * 16384 + (IT) * 4096 + wid * 512)

  f32x4 acc[8][4];
  const f32x4 zero = {0.f, 0.f, 0.f, 0.f};
#pragma unroll
  for (int i = 0; i < 8; ++i)
#pragma unroll
    for (int j = 0; j < 4; ++j) acc[i][j] = zero;

  // prologue: stage tile 0 -> parity 0
  DB1(0, 0, 0); DB1(0, 0, 1); DB1(0, 0, 2); DB1(0, 0, 3);
  DA1(0, 0, 0); DA1(0, 0, 1); DA1(0, 0, 2); DA1(0, 0, 3);
  SCHB;
  WAIT_VM(0);
  SBAR;
  SCHB;

  const int NK = IDIM / 64;   // 224
#pragma unroll 1
  for (int kt = 0; kt < NK; ++kt) {
    const int RD = kt & 1, WR = RD ^ 1;
    const int ktn = (kt + 1 < NK) ? kt + 1 : NK - 1;
    const unsigned short* Ab = (const unsigned short*)As + RD * 16384;
    const unsigned short* Bb = (const unsigned short*)Bs + RD * 16384;
    const int soff0 = (lc ^ (lr & 7)) << 3;
    const int soff1 = ((4 + lc) ^ (lr & 7)) << 3;
    bf16x8 af[8], bfr[4];

    // ---- ph0: ks0 ----
#pragma unroll
    for (int mi = 0; mi < 8; ++mi)
      af[mi] = *(const bf16x8*)&Ab[(wm * 128 + mi * 16 + lr) * 64 + soff0];
#pragma unroll
    for (int ni = 0; ni < 4; ++ni)
      bfr[ni] = *(const bf16x8*)&Bb[(wn * 64 + ni * 16 + lr) * 64 + soff0];
    DB1(ktn, WR, 0); DB1(ktn, WR, 1); DB1(ktn, WR, 2); DB1(ktn, WR, 3);
    SCHB; WAIT_LGKM0; SCHB;
    __builtin_amdgcn_s_setprio(1);
#pragma unroll
    for (int ni = 0; ni < 4; ++ni)
#pragma unroll
      for (int mi = 0; mi < 8; ++mi)
        acc[mi][ni] = __builtin_amdgcn_mfma_f32_16x16x32_bf16(af[mi], bfr[ni], acc[mi][ni], 0, 0, 0);
    __builtin_amdgcn_s_setprio(0);

    // ---- ph1: ks1 ----
#pragma unroll
    for (int mi = 0; mi < 8; ++mi)
      af[mi] = *(const bf16x8*)&Ab[(wm * 128 + mi * 16 + lr) * 64 + soff1];
#pragma unroll
    for (int ni = 0; ni < 4; ++ni)
      bfr[ni] = *(const bf16x8*)&Bb[(wn * 64 + ni * 16 + lr) * 64 + soff1];
    DA1(ktn, WR, 0); DA1(ktn, WR, 1); DA1(ktn, WR, 2); DA1(ktn, WR, 3);
    SCHB; WAIT_LGKM0; SCHB;
    __builtin_amdgcn_s_setprio(1);
#pragma unroll
    for (int ni = 0; ni < 4; ++ni)
#pragma unroll
      for (int mi = 0; mi < 8; ++mi)
        acc[mi][ni] = __builtin_amdgcn_mfma_f32_16x16x32_bf16(af[mi], bfr[ni], acc[mi][ni], 0, 0, 0);
    __builtin_amdgcn_s_setprio(0);

    // ---- tail: retire next-tile stage, rendezvous ----
    SCHB;
    WAIT_VM(0);
    SBAR;
    SCHB;
  }

  const int r0 = m0 + wm * 128, c0 = n0 + wn * 64;
#pragma unroll
  for (int mi = 0; mi < 8; ++mi)
#pragma unroll
    for (int ni = 0; ni < 4; ++ni)
#pragma unroll
      for (int r = 0; r < 4; ++r) {
        int row = r0 + mi * 16 + lc * 4 + r;
        int col = c0 + ni * 16 + lr;
        out[(long)row * HDIM + col] = acc[mi][ni][r];
      }
#undef DA1
#undef DB1
}

extern "C" void kernel_launch(void* const* d_in, const int* in_sizes, int n_in,
                              void* d_out, int out_size, void* d_ws, size_t ws_size,
                              hipStream_t stream) {
  const float* x   = (const float*)d_in[0];
  const int*   gq  = (const int*)d_in[1];
  const float* gsc = (const float*)d_in[2];
  const int*   uq  = (const int*)d_in[3];
  const float* usc = (const float*)d_in[4];
  const int*   dq  = (const int*)d_in[5];
  const float* dsc = (const float*)d_in[6];
  float* out = (float*)d_out;

  unsigned short* xb    = (unsigned short*)d_ws;                    // 32 MiB
  unsigned short* inter = xb + (size_t)MTOK * HDIM;                 // 112 MiB
  unsigned short* wgb   = inter + (size_t)MTOK * IDIM;              // 112 MiB
  unsigned short* wub   = wgb + (size_t)IDIM * HDIM;                // 112 MiB

  hipLaunchKernelGGL(cvt_x_kernel, dim3(2048), dim3(256), 0, stream, x, xb);
  hipLaunchKernelGGL(deq_kernel, dim3(HDIM / 2048, IDIM), dim3(256), 0, stream,
                     gq, gsc, wgb, HDIM);
  hipLaunchKernelGGL(deq_kernel, dim3(HDIM / 2048, IDIM), dim3(256), 0, stream,
                     uq, usc, wub, HDIM);
  hipLaunchKernelGGL(gateup_bf16, dim3(1792), dim3(512), 0, stream,
                     xb, wgb, wub, inter);
  // down weights reuse the (now free) gate-weight region
  hipLaunchKernelGGL(deq_kernel, dim3(IDIM / 2048, HDIM), dim3(256), 0, stream,
                     dq, dsc, wgb, IDIM);
  hipLaunchKernelGGL(down_bf16, dim3(256), dim3(512), 0, stream,
                     inter, wgb, out);
}